// Round 8
// baseline (18190.483 us; speedup 1.0000x reference)
//
#include <hip/hip_runtime.h>

#define L_SEQ 513
#define DM 768
#define DI 1536
#define DSTATE 16
#define DTRANK 48
#define NCLS 527
#define DEPTH 24
#define NC 32
#define CLEN 17
#define SKI 2     // split-K for in_proj (768 = 2*384)
#define SKO 8     // split-K for out_proj (1536 = 8*192)
#define NBLK 256  // 1 block/CU -> co-residency guaranteed

typedef unsigned short u16;
typedef unsigned int u32;
typedef __bf16 bf16x8 __attribute__((ext_vector_type(8)));
typedef float f32x4 __attribute__((ext_vector_type(4)));

#define MFMA_BF16(A, B, C) __builtin_amdgcn_mfma_f32_16x16x32_bf16(A, B, C, 0, 0, 0)

__device__ inline u16 f2bf(float x) {
  unsigned u = __float_as_uint(x);
  return (u16)((u + 0x7FFFu + ((u >> 16) & 1u)) >> 16);
}
__device__ inline float bf2f(u16 h) { return __uint_as_float((unsigned)h << 16); }
__device__ inline void split2(float v, u16& h, u16& l) {
  h = f2bf(v);
  l = f2bf(v - bf2f(h));
}
__device__ __forceinline__ int lofs(int row, int g) {
  int swz = (row & 3) ^ ((row >> 2) & 3);
  return row * 32 + ((g ^ swz) << 3);
}
__device__ inline float siluf(float v) { return v / (1.f + __expf(-v)); }

// ---------------- device-scope grid barrier (arrive flags + epoch) ----------------
__device__ __forceinline__ void grid_sync(u32* flags, u32* epoch, u32 e) {
  __syncthreads();
  if (blockIdx.x == 0) {
    if (threadIdx.x == 0)
      __hip_atomic_store(&flags[0], e, __ATOMIC_RELEASE, __HIP_MEMORY_SCOPE_AGENT);
    int b = threadIdx.x;  // 256 threads poll 256 flags
    while (__hip_atomic_load(&flags[b * 16], __ATOMIC_ACQUIRE, __HIP_MEMORY_SCOPE_AGENT) < e)
      __builtin_amdgcn_s_sleep(1);
    __syncthreads();
    if (threadIdx.x == 0)
      __hip_atomic_store(epoch, e, __ATOMIC_RELEASE, __HIP_MEMORY_SCOPE_AGENT);
  } else {
    if (threadIdx.x == 0) {
      __hip_atomic_store(&flags[blockIdx.x * 16], e, __ATOMIC_RELEASE, __HIP_MEMORY_SCOPE_AGENT);
      while (__hip_atomic_load(epoch, __ATOMIC_ACQUIRE, __HIP_MEMORY_SCOPE_AGENT) < e)
        __builtin_amdgcn_s_sleep(1);
    }
  }
  __syncthreads();
}

// ---------------- 128x128 hi/lo MFMA GEMM tile (device fn, shared LDS) ----------------
// AMODE 0: A pre-split u16 hi/lo. AMODE 1: A = 0.5*(A0+A1) fp32, split on the fly.
template <int AMODE>
__device__ void gemm_tile(const void* A0, const void* A1,
                          const u16* __restrict__ Bh, const u16* __restrict__ Bl,
                          float* __restrict__ Cb, int M, int N, int K,
                          int lda, int ldb, int ldc,
                          int m0, int n0, int ks0, int kend,
                          const float* biasp, int act,
                          u16* d48h, u16* d48l, int ncap, int ldhl,
                          u16* LDSU) {
  u16* SA = LDSU;           // [buf][hl][4096] -> ((buf<<1)|hl)*4096
  u16* SB = LDSU + 16384;

  int tid = threadIdx.x;
  int r0 = tid >> 2, g0 = tid & 3;
  int r1 = r0 + 64;
  int l0 = lofs(r0, g0), l1 = lofs(r1, g0);
  const u16* Ahb = (const u16*)A0;
  const u16* Alb = (const u16*)A1;
  const float* Af = (const float*)A0;
  const float* Ag = (const float*)A1;
  const u16* Bhb = Bh;
  const u16* Blb = Bl;
  long aoff0 = (long)(m0 + r0) * lda, aoff1 = (long)(m0 + r1) * lda;
  long boff0 = (long)(n0 + r0) * ldb, boff1 = (long)(n0 + r1) * ldb;
  bool am0 = (m0 + r0) < M, am1 = (m0 + r1) < M;
  bool bm0 = (n0 + r0) < N, bm1 = (n0 + r1) < N;

  int lane = tid & 63, w = tid >> 6;
  int wr = w >> 1, wc = w & 1;
  int fr = lane & 15, kh = lane >> 4;
  int offA[4], offB[4];
#pragma unroll
  for (int i = 0; i < 4; ++i) {
    offA[i] = lofs(wr * 64 + i * 16 + fr, kh);
    offB[i] = lofs(wc * 64 + i * 16 + fr, kh);
  }

  uint4 a0h, a1h, a0l, a1l, b0h, b1h, b0l, b1l;
  auto loadA = [&](long rowoff, bool ok, int k_, uint4& hh, uint4& ll) {
    uint4 z4 = {0, 0, 0, 0};
    if (AMODE == 0) {
      hh = ok ? *(const uint4*)(Ahb + rowoff + k_) : z4;
      ll = ok ? *(const uint4*)(Alb + rowoff + k_) : z4;
    } else {
      if (!ok) { hh = z4; ll = z4; return; }
      float4 f0 = *(const float4*)(Af + rowoff + k_);
      float4 f1 = *(const float4*)(Af + rowoff + k_ + 4);
      float4 g0v = *(const float4*)(Ag + rowoff + k_);
      float4 g1v = *(const float4*)(Ag + rowoff + k_ + 4);
      u16 ha[8], la[8];
      split2(0.5f * (f0.x + g0v.x), ha[0], la[0]);
      split2(0.5f * (f0.y + g0v.y), ha[1], la[1]);
      split2(0.5f * (f0.z + g0v.z), ha[2], la[2]);
      split2(0.5f * (f0.w + g0v.w), ha[3], la[3]);
      split2(0.5f * (f1.x + g1v.x), ha[4], la[4]);
      split2(0.5f * (f1.y + g1v.y), ha[5], la[5]);
      split2(0.5f * (f1.z + g1v.z), ha[6], la[6]);
      split2(0.5f * (f1.w + g1v.w), ha[7], la[7]);
      hh = *(const uint4*)ha;
      ll = *(const uint4*)la;
    }
  };
  auto loadstep = [&](int kb) {
    int k_ = kb + g0 * 8;
    bool kk = (k_ + 8 <= kend);
    uint4 z4 = {0, 0, 0, 0};
    loadA(aoff0, kk && am0, k_, a0h, a0l);
    loadA(aoff1, kk && am1, k_, a1h, a1l);
    b0h = (kk && bm0) ? *(const uint4*)(Bhb + boff0 + k_) : z4;
    b1h = (kk && bm1) ? *(const uint4*)(Bhb + boff1 + k_) : z4;
    b0l = (kk && bm0) ? *(const uint4*)(Blb + boff0 + k_) : z4;
    b1l = (kk && bm1) ? *(const uint4*)(Blb + boff1 + k_) : z4;
  };
  auto writebuf = [&](int b) {
    *(uint4*)&SA[((b << 1) | 0) * 4096 + l0] = a0h;
    *(uint4*)&SA[((b << 1) | 0) * 4096 + l1] = a1h;
    *(uint4*)&SA[((b << 1) | 1) * 4096 + l0] = a0l;
    *(uint4*)&SA[((b << 1) | 1) * 4096 + l1] = a1l;
    *(uint4*)&SB[((b << 1) | 0) * 4096 + l0] = b0h;
    *(uint4*)&SB[((b << 1) | 0) * 4096 + l1] = b1h;
    *(uint4*)&SB[((b << 1) | 1) * 4096 + l0] = b0l;
    *(uint4*)&SB[((b << 1) | 1) * 4096 + l1] = b1l;
  };

  f32x4 acc[4][4] = {};
  int nst = (kend - ks0 + 31) >> 5;
  loadstep(ks0);
  writebuf(0);
  if (nst > 1) loadstep(ks0 + 32);
  __syncthreads();

  for (int s = 0; s < nst; ++s) {
    int b = s & 1;
    bf16x8 fah[4], fal[4], fbh[4], fbl[4];
#pragma unroll
    for (int i = 0; i < 4; ++i) {
      fah[i] = __builtin_bit_cast(bf16x8, *(const uint4*)&SA[((b << 1) | 0) * 4096 + offA[i]]);
      fal[i] = __builtin_bit_cast(bf16x8, *(const uint4*)&SA[((b << 1) | 1) * 4096 + offA[i]]);
      fbh[i] = __builtin_bit_cast(bf16x8, *(const uint4*)&SB[((b << 1) | 0) * 4096 + offB[i]]);
      fbl[i] = __builtin_bit_cast(bf16x8, *(const uint4*)&SB[((b << 1) | 1) * 4096 + offB[i]]);
    }
#pragma unroll
    for (int mi = 0; mi < 4; ++mi)
#pragma unroll
      for (int ni = 0; ni < 4; ++ni) {
        acc[mi][ni] = MFMA_BF16(fah[mi], fbh[ni], acc[mi][ni]);
        acc[mi][ni] = MFMA_BF16(fah[mi], fbl[ni], acc[mi][ni]);
        acc[mi][ni] = MFMA_BF16(fal[mi], fbh[ni], acc[mi][ni]);
      }
    if (s + 1 < nst) {
      writebuf(b ^ 1);
      if (s + 2 < nst) loadstep(ks0 + (s + 2) * 32);
    }
    __syncthreads();
  }

#pragma unroll
  for (int mi = 0; mi < 4; ++mi)
#pragma unroll
    for (int ni = 0; ni < 4; ++ni) {
      int n = n0 + wc * 64 + ni * 16 + fr;
      if (n >= N) continue;
      float bv = biasp ? biasp[n] : 0.f;
#pragma unroll
      for (int r = 0; r < 4; ++r) {
        int m = m0 + wr * 64 + mi * 16 + kh * 4 + r;
        if (m >= M) continue;
        float v = acc[mi][ni][r] + bv;
        if (act == 1) v = (v > 20.f) ? v : log1pf(__expf(v));
        Cb[(long)m * ldc + n] = v;
        if (d48h && n < ncap) {
          u16 hh, ll;
          split2(v, hh, ll);
          d48h[(long)m * ldhl + n] = hh;
          d48l[(long)m * ldhl + n] = ll;
        }
      }
    }
}

// ---------------- standalone pre-kernels ----------------
__global__ void wconvert_kernel(const float* __restrict__ src,
                                u16* __restrict__ hi, u16* __restrict__ lo,
                                long n4) {
  long i = (long)blockIdx.x * 256 + threadIdx.x;
  long stride = (long)gridDim.x * 256;
  for (; i < n4; i += stride) {
    float4 v = ((const float4*)src)[i];
    ushort4 h, l;
    split2(v.x, h.x, l.x);
    split2(v.y, h.y, l.y);
    split2(v.z, h.z, l.z);
    split2(v.w, h.w, l.w);
    ((ushort4*)hi)[i] = h;
    ((ushort4*)lo)[i] = l;
  }
}

__global__ void patch_embed_kernel(const float* __restrict__ x,
                                   const float* __restrict__ pw,
                                   const float* __restrict__ pb,
                                   const float* __restrict__ cls,
                                   const float* __restrict__ pos,
                                   float* __restrict__ hidden,
                                   float* __restrict__ residual) {
  int c = blockIdx.x * 256 + threadIdx.x;
  int s = blockIdx.y;
  if (c >= DM) return;
  float val;
  if (s == 256) {
    val = cls[c];
  } else {
    int p = s - (s > 256 ? 1 : 0);
    int gy = p >> 6, gx = p & 63;
    const float* xp = x + gy * 16 * 1024 + gx * 16;
    const float* wp = pw + c * 256;
    float acc = pb[c];
#pragma unroll 4
    for (int ky = 0; ky < 16; ++ky)
#pragma unroll
      for (int kx = 0; kx < 16; ++kx)
        acc += xp[ky * 1024 + kx] * wp[ky * 16 + kx];
    val = acc;
  }
  long idx = (long)s * DM + c;
  hidden[idx] = val + pos[idx];
  residual[idx] = 0.f;
}

// ---------------- the megakernel: 24 layers + head, grid-synced ----------------
__global__ __launch_bounds__(256, 2) void mega(
    const float* __restrict__ conv_w, const float* __restrict__ conv_b,
    const float* __restrict__ dtproj_b, const float* __restrict__ A_log,
    const float* __restrict__ D_skip, const float* __restrict__ norm_w,
    const float* __restrict__ norm_f_w, const float* __restrict__ head_w,
    const float* __restrict__ head_b,
    float* residual, float* xz_p, float* xc, float* zs, float* dbl,
    float* dtb, float* yb, float* hid_p,
    u16* hn_h, u16* hn_l, u16* xc_h, u16* xc_l, u16* d48_h, u16* d48_l,
    const u16* wi_h, const u16* wi_l, const u16* wx_h, const u16* wx_l,
    const u16* wd_h, const u16* wd_l, const u16* wo_h, const u16* wo_l,
    u32* flags, u32* epoch, float* out) {
  __shared__ __align__(16) u16 LDSU[32768];  // 64 KB
  const int bid = blockIdx.x;
  const int tid = threadIdx.x;
  const long PHN = (long)L_SEQ * DM;
  const long PZ = (long)L_SEQ * 2 * DI;
  const long LDIlen = (long)L_SEQ * DI;
  u32 e = 0;

  for (int l = 0; l < DEPTH; ++l) {
    const u16* wih = wi_h + (long)l * 2 * DI * DM;
    const u16* wil = wi_l + (long)l * 2 * DI * DM;
    const u16* wxh = wx_h + (long)l * 2 * 80 * DI;
    const u16* wxl = wx_l + (long)l * 2 * 80 * DI;
    const u16* wdh = wd_h + (long)l * 2 * DI * DTRANK;
    const u16* wdl = wd_l + (long)l * 2 * DI * DTRANK;
    const u16* woh = wo_h + (long)l * DM * DI;
    const u16* wol = wo_l + (long)l * DM * DI;
    const float* cw = conv_w + (long)l * 2 * DI * 4;
    const float* cb = conv_b + (long)l * 2 * DI;
    const float* db = dtproj_b + (long)l * 2 * DI;
    const float* Al = A_log + (long)l * 2 * DI * DSTATE;
    const float* Dk = D_skip + (long)l * 2 * DI;
    const float* nw = norm_w + (long)l * DM;
    int nparts = (l == 0) ? 1 : SKO;

    // ---- P1: residual += partials; hn = rmsnorm -> hi/lo ----
    for (int t = bid; t < L_SEQ; t += NBLK) {
      float* rrow = residual + (long)t * DM;
      float vals[3];
      float ss = 0.f;
#pragma unroll
      for (int i = 0; i < 3; ++i) {
        int c = tid + i * 256;
        float v = rrow[c];
        for (int p = 0; p < nparts; ++p) v += hid_p[(long)p * PHN + (long)t * DM + c];
        vals[i] = v;
        rrow[c] = v;
        ss += v * v;
      }
#pragma unroll
      for (int o = 32; o; o >>= 1) ss += __shfl_down(ss, o, 64);
      float* sacc = (float*)LDSU;
      if ((tid & 63) == 0) sacc[tid >> 6] = ss;
      __syncthreads();
      float tot = sacc[0] + sacc[1] + sacc[2] + sacc[3];
      float rs = rsqrtf(tot / (float)DM + 1e-5f);
      __syncthreads();
#pragma unroll
      for (int i = 0; i < 3; ++i) {
        int c = tid + i * 256;
        float y = vals[i] * rs * nw[c];
        u16 h, lo;
        split2(y, h, lo);
        hn_h[(long)t * DM + c] = h;
        hn_l[(long)t * DM + c] = lo;
      }
    }
    e++; grid_sync(flags, epoch, e);

    // ---- P2: in_proj, split-K=2: 24 x 5 x 2 = 240 tiles ----
    for (int vt = bid; vt < 24 * 5 * SKI; vt += NBLK) {
      int sk = vt & (SKI - 1), rest = vt >> 1;
      int my = rest / 24, nx = rest % 24;
      gemm_tile<0>(hn_h, hn_l, wih, wil, xz_p + (long)sk * PZ,
                   L_SEQ, 2 * DI, DM, DM, DM, 2 * DI,
                   my * 128, nx * 128, sk * 384, min(DM, sk * 384 + 384),
                   nullptr, 0, nullptr, nullptr, 0, 0, LDSU);
    }
    e++; grid_sync(flags, epoch, e);

    // ---- P3: conv+silu -> xc (+hi/lo); silu(z) -> zs ----
    for (int v = bid; v < 2310; v += NBLK) {
      if (v < 1540) {
        int dir = v / 770, vv = v - dir * 770;
        int idx = vv * 256 + tid;
        if (idx < L_SEQ * (DI / 4)) {
          int d4 = idx % (DI / 4);
          int t = idx / (DI / 4);
          int d = d4 * 4;
          float wv[4][4];
#pragma unroll
          for (int j = 0; j < 4; ++j) {
            float4 wr4 = *(const float4*)(cw + ((long)dir * DI + d + j) * 4);
            wv[j][0] = wr4.x; wv[j][1] = wr4.y; wv[j][2] = wr4.z; wv[j][3] = wr4.w;
          }
          float4 bv = *(const float4*)(cb + (long)dir * DI + d);
          float a0 = bv.x, a1 = bv.y, a2 = bv.z, a3 = bv.w;
#pragma unroll
          for (int k = 0; k < 4; ++k) {
            int tau = t + k - 3;
            if (tau >= 0) {
              int tsrc = dir ? (L_SEQ - 1 - tau) : tau;
              long o = (long)tsrc * (2 * DI) + d;
              float4 x0 = *(const float4*)(xz_p + o);
              float4 x1 = *(const float4*)(xz_p + o + PZ);
              a0 += wv[0][k] * (x0.x + x1.x);
              a1 += wv[1][k] * (x0.y + x1.y);
              a2 += wv[2][k] * (x0.z + x1.z);
              a3 += wv[3][k] * (x0.w + x1.w);
            }
          }
          float4 sv;
          sv.x = siluf(a0); sv.y = siluf(a1); sv.z = siluf(a2); sv.w = siluf(a3);
          long o = ((long)dir * L_SEQ + t) * DI + d;
          *(float4*)(xc + o) = sv;
          ushort4 h, lo;
          split2(sv.x, h.x, lo.x);
          split2(sv.y, h.y, lo.y);
          split2(sv.z, h.z, lo.z);
          split2(sv.w, h.w, lo.w);
          *(ushort4*)(xc_h + o) = h;
          *(ushort4*)(xc_l + o) = lo;
        }
      } else {
        int vv = v - 1540;
        int idx = vv * 256 + tid;
        if (idx < L_SEQ * (DI / 4)) {
          int d4 = idx % (DI / 4);
          int t = idx / (DI / 4);
          long zo = (long)t * (2 * DI) + DI + d4 * 4;
          float4 z0 = *(const float4*)(xz_p + zo);
          float4 z1 = *(const float4*)(xz_p + zo + PZ);
          float4 sv;
          sv.x = siluf(z0.x + z1.x);
          sv.y = siluf(z0.y + z1.y);
          sv.z = siluf(z0.z + z1.z);
          sv.w = siluf(z0.w + z1.w);
          *(float4*)(zs + (long)t * DI + d4 * 4) = sv;
        }
      }
    }
    e++; grid_sync(flags, epoch, e);

    // ---- P4: x_proj (10 tiles): dbl fp32 + d48 hi/lo ----
    if (bid < 10) {
      int dir = bid / 5, my = bid % 5;
      gemm_tile<0>(xc_h + dir * LDIlen, xc_l + dir * LDIlen,
                   wxh + (long)dir * 80 * DI, wxl + (long)dir * 80 * DI,
                   dbl + (long)dir * L_SEQ * 80,
                   L_SEQ, 80, DI, DI, DI, 80,
                   my * 128, 0, 0, DI,
                   nullptr, 0,
                   d48_h + (long)dir * L_SEQ * DTRANK,
                   d48_l + (long)dir * L_SEQ * DTRANK, DTRANK, DTRANK, LDSU);
    }
    e++; grid_sync(flags, epoch, e);

    // ---- P5: dt_proj (12 x 5 x 2 = 120 tiles): softplus(d48 @ dw^T + db) ----
    for (int vt = bid; vt < 120; vt += NBLK) {
      int dir = vt / 60, r = vt - dir * 60;
      int my = r / 12, nx = r % 12;
      gemm_tile<0>(d48_h + (long)dir * L_SEQ * DTRANK, d48_l + (long)dir * L_SEQ * DTRANK,
                   wdh + (long)dir * DI * DTRANK, wdl + (long)dir * DI * DTRANK,
                   dtb + dir * LDIlen,
                   L_SEQ, DI, DTRANK, DTRANK, DTRANK, DI,
                   my * 128, nx * 128, 0, DTRANK,
                   db + dir * DI, 1, nullptr, nullptr, 0, 0, LDSU);
    }
    e++; grid_sync(flags, epoch, e);

    // ---- P6: chunked scan (block-local fixup) ----
    for (int vb = bid; vb < 384; vb += NBLK) {
      int dir = vb / 192, d0 = (vb - dir * 192) * 8;
      float* Q = (float*)LDSU;              // [8][NC][16]
      float* Sv = (float*)LDSU + 4096;      // [8][NC]
      const float* dtp = dtb + dir * LDIlen;
      const float* xcp = xc + dir * LDIlen;
      const float* dblp = dbl + (long)dir * L_SEQ * 80;
      int dl = tid & 7, c = tid >> 3;
      int d = d0 + dl;
      float negA[DSTATE];
#pragma unroll
      for (int n = 0; n < DSTATE; ++n)
        negA[n] = -__expf(Al[((long)dir * DI + d) * DSTATE + n]);
      int t0 = c * CLEN, t1 = min(t0 + CLEN, L_SEQ);
      {
        float h[DSTATE];
#pragma unroll
        for (int n = 0; n < DSTATE; ++n) h[n] = 0.f;
        float S = 0.f;
        for (int t = t0; t < t1; ++t) {
          float dt = dtp[(long)t * DI + d];
          float u = xcp[(long)t * DI + d];
          float du = dt * u;
          S += dt;
          const float4* B4 = (const float4*)(dblp + (long)t * 80 + DTRANK);
          float4 b0 = B4[0], b1 = B4[1], b2 = B4[2], b3 = B4[3];
          float Bv[DSTATE] = {b0.x, b0.y, b0.z, b0.w, b1.x, b1.y, b1.z, b1.w,
                              b2.x, b2.y, b2.z, b2.w, b3.x, b3.y, b3.z, b3.w};
#pragma unroll
          for (int n = 0; n < DSTATE; ++n)
            h[n] = h[n] * __expf(dt * negA[n]) + du * Bv[n];
        }
        Sv[dl * NC + c] = S;
#pragma unroll
        for (int n = 0; n < DSTATE; ++n) Q[(dl * NC + c) * DSTATE + n] = h[n];
      }
      __syncthreads();
      if (tid < 128) {
        int fdl = tid >> 4, n = tid & 15;
        int fd = d0 + fdl;
        float nA = -__expf(Al[((long)dir * DI + fd) * DSTATE + n]);
        float h = 0.f;
        for (int cc = 0; cc < NC; ++cc) {
          float S = Sv[fdl * NC + cc];
          float q = Q[(fdl * NC + cc) * DSTATE + n];
          Q[(fdl * NC + cc) * DSTATE + n] = h;
          h = h * __expf(nA * S) + q;
        }
      }
      __syncthreads();
      {
        float h[DSTATE];
#pragma unroll
        for (int n = 0; n < DSTATE; ++n) h[n] = Q[(dl * NC + c) * DSTATE + n];
        float dskip = Dk[(long)dir * DI + d];
        for (int t = t0; t < t1; ++t) {
          float dt = dtp[(long)t * DI + d];
          float u = xcp[(long)t * DI + d];
          float du = dt * u;
          const float4* B4 = (const float4*)(dblp + (long)t * 80 + DTRANK);
          float4 b0 = B4[0], b1 = B4[1], b2 = B4[2], b3 = B4[3];
          float4 c0 = B4[4], c1 = B4[5], c2 = B4[6], c3 = B4[7];
          float Bv[DSTATE] = {b0.x, b0.y, b0.z, b0.w, b1.x, b1.y, b1.z, b1.w,
                              b2.x, b2.y, b2.z, b2.w, b3.x, b3.y, b3.z, b3.w};
          float Cv[DSTATE] = {c0.x, c0.y, c0.z, c0.w, c1.x, c1.y, c1.z, c1.w,
                              c2.x, c2.y, c2.z, c2.w, c3.x, c3.y, c3.z, c3.w};
          float acc = 0.f;
#pragma unroll
          for (int n = 0; n < DSTATE; ++n) {
            h[n] = h[n] * __expf(dt * negA[n]) + du * Bv[n];
            acc += h[n] * Cv[n];
          }
          int tsrc = dir ? (L_SEQ - 1 - t) : t;
          float sz = zs[(long)tsrc * DI + d];
          yb[((long)dir * L_SEQ + tsrc) * DI + d] = (acc + dskip * u) * sz;
        }
      }
      __syncthreads();
    }
    e++; grid_sync(flags, epoch, e);

    // ---- P7: out_proj, fused yavg, split-K=8: 6 x 5 x 8 = 240 tiles ----
    for (int vt = bid; vt < 240; vt += NBLK) {
      int sk = vt & 7, rest = vt >> 3;
      int my = rest / 6, nx = rest % 6;
      gemm_tile<1>(yb, yb + LDIlen, woh, wol, hid_p + (long)sk * PHN,
                   L_SEQ, DM, DI, DI, DI, DM,
                   my * 128, nx * 128, sk * 192, sk * 192 + 192,
                   nullptr, 0, nullptr, nullptr, 0, 0, LDSU);
    }
    e++; grid_sync(flags, epoch, e);
  }

  // ---- head: final rmsnorm(token 256) + classifier ----
  for (int j = bid; j < NCLS; j += NBLK) {
    const float* r = residual + (long)256 * DM;
    float ss = 0.f, dp = 0.f;
#pragma unroll
    for (int i = 0; i < 3; ++i) {
      int c = tid + i * 256;
      float v = r[c];
      for (int p = 0; p < SKO; ++p) v += hid_p[(long)p * PHN + (long)256 * DM + c];
      ss += v * v;
      dp += v * norm_f_w[c] * head_w[(long)j * DM + c];
    }
#pragma unroll
    for (int o = 32; o; o >>= 1) {
      ss += __shfl_down(ss, o, 64);
      dp += __shfl_down(dp, o, 64);
    }
    float* s1 = (float*)LDSU;
    float* s2 = (float*)LDSU + 8;
    if ((tid & 63) == 0) {
      s1[tid >> 6] = ss;
      s2[tid >> 6] = dp;
    }
    __syncthreads();
    if (tid == 0) {
      float tot = s1[0] + s1[1] + s1[2] + s1[3];
      float dd = s2[0] + s2[1] + s2[2] + s2[3];
      out[j] = dd * rsqrtf(tot / (float)DM + 1e-5f) + head_b[j];
    }
    __syncthreads();
  }
}

extern "C" void kernel_launch(void* const* d_in, const int* in_sizes, int n_in,
                              void* d_out, int out_size, void* d_ws, size_t ws_size,
                              hipStream_t stream) {
  const float* x        = (const float*)d_in[0];
  const float* patch_w  = (const float*)d_in[1];
  const float* patch_b  = (const float*)d_in[2];
  const float* cls_tok  = (const float*)d_in[3];
  const float* pos_emb  = (const float*)d_in[4];
  const float* in_proj  = (const float*)d_in[5];
  const float* conv_w   = (const float*)d_in[6];
  const float* conv_b   = (const float*)d_in[7];
  const float* xproj_w  = (const float*)d_in[8];
  const float* dtproj_w = (const float*)d_in[9];
  const float* dtproj_b = (const float*)d_in[10];
  const float* A_log    = (const float*)d_in[11];
  const float* D_skip   = (const float*)d_in[12];
  const float* out_proj = (const float*)d_in[13];
  const float* norm_w   = (const float*)d_in[14];
  const float* norm_f_w = (const float*)d_in[15];
  const float* head_w   = (const float*)d_in[16];
  const float* head_b   = (const float*)d_in[17];
  float* out = (float*)d_out;

  const long PHN = (long)L_SEQ * DM;
  const long PZ  = (long)L_SEQ * 2 * DI;

  char* base = (char*)d_ws;
  u32* flags = (u32*)base;                 // 256 * 64 B
  u32* epoch = (u32*)(base + NBLK * 64);
  float* fb = (float*)(base + 32768);
  float* residual = fb; fb += PHN;
  float* xz_p     = fb; fb += SKI * PZ;
  float* xc       = fb; fb += (long)2 * L_SEQ * DI;
  float* zs       = fb; fb += (long)L_SEQ * DI;
  float* dbl      = fb; fb += (long)2 * L_SEQ * 80;
  float* dtb      = fb; fb += (long)2 * L_SEQ * DI;
  float* yb       = fb; fb += (long)2 * L_SEQ * DI;
  float* hid_p    = fb; fb += (long)SKO * PHN;

  u16* wsu = (u16*)fb;
  const long N_HN = PHN;
  const long N_XC = (long)2 * L_SEQ * DI;
  const long N_D48 = (long)2 * L_SEQ * DTRANK;
  const long N_WI = (long)DEPTH * 2 * DI * DM;
  const long N_WX = (long)DEPTH * 2 * 80 * DI;
  const long N_WD = (long)DEPTH * 2 * DI * DTRANK;
  const long N_WO = (long)DEPTH * DM * DI;
  u16* hn_h = wsu; wsu += N_HN;
  u16* hn_l = wsu; wsu += N_HN;
  u16* xc_h = wsu; wsu += N_XC;
  u16* xc_l = wsu; wsu += N_XC;
  u16* d48_h = wsu; wsu += N_D48;
  u16* d48_l = wsu; wsu += N_D48;
  u16* wi_h = wsu; wsu += N_WI;
  u16* wi_l = wsu; wsu += N_WI;
  u16* wx_h = wsu; wsu += N_WX;
  u16* wx_l = wsu; wsu += N_WX;
  u16* wd_h = wsu; wsu += N_WD;
  u16* wd_l = wsu; wsu += N_WD;
  u16* wo_h = wsu; wsu += N_WO;
  u16* wo_l = wsu; wsu += N_WO;

  // reset barrier state (replay-safe)
  (void)hipMemsetAsync(d_ws, 0, 32768, stream);

  wconvert_kernel<<<2048, 256, 0, stream>>>(in_proj,  wi_h, wi_l, N_WI / 4);
  wconvert_kernel<<<512,  256, 0, stream>>>(xproj_w,  wx_h, wx_l, N_WX / 4);
  wconvert_kernel<<<512,  256, 0, stream>>>(dtproj_w, wd_h, wd_l, N_WD / 4);
  wconvert_kernel<<<2048, 256, 0, stream>>>(out_proj, wo_h, wo_l, N_WO / 4);

  patch_embed_kernel<<<dim3(3, L_SEQ), 256, 0, stream>>>(
      x, patch_w, patch_b, cls_tok, pos_emb, hid_p, residual);

  mega<<<NBLK, 256, 0, stream>>>(
      conv_w, conv_b, dtproj_b, A_log, D_skip, norm_w, norm_f_w, head_w, head_b,
      residual, xz_p, xc, zs, dbl, dtb, yb, hid_p,
      hn_h, hn_l, xc_h, xc_l, d48_h, d48_l,
      wi_h, wi_l, wx_h, wx_l, wd_h, wd_l, wo_h, wo_l,
      flags, epoch, out);
}

// Round 10
// 10408.569 us; speedup vs baseline: 1.7476x; 1.7476x over previous
//
#include <hip/hip_runtime.h>
#include <hip/hip_cooperative_groups.h>

namespace cg = cooperative_groups;

#define L_SEQ 513
#define DM 768
#define DI 1536
#define DSTATE 16
#define DTRANK 48
#define NCLS 527
#define DEPTH 24
#define NC 32
#define CLEN 17
#define SKI 2     // split-K for in_proj (768 = 2*384)
#define SKO 8     // split-K for out_proj (1536 = 8*192)
#define NBLK 256  // 1 block/CU -> co-residency guaranteed

typedef unsigned short u16;
typedef unsigned int u32;
typedef __bf16 bf16x8 __attribute__((ext_vector_type(8)));
typedef float f32x4 __attribute__((ext_vector_type(4)));

#define MFMA_BF16(A, B, C) __builtin_amdgcn_mfma_f32_16x16x32_bf16(A, B, C, 0, 0, 0)

__device__ inline u16 f2bf(float x) {
  unsigned u = __float_as_uint(x);
  return (u16)((u + 0x7FFFu + ((u >> 16) & 1u)) >> 16);
}
__device__ inline float bf2f(u16 h) { return __uint_as_float((unsigned)h << 16); }
__device__ inline void split2(float v, u16& h, u16& l) {
  h = f2bf(v);
  l = f2bf(v - bf2f(h));
}
__device__ __forceinline__ int lofs(int row, int g) {
  int swz = (row & 3) ^ ((row >> 2) & 3);
  return row * 32 + ((g ^ swz) << 3);
}
__device__ inline float siluf(float v) { return v / (1.f + __expf(-v)); }

// ---------------- 128x128 hi/lo MFMA GEMM tile (device fn, shared LDS) ----------------
// AMODE 0: A pre-split u16 hi/lo. AMODE 1: A = 0.5*(A0+A1) fp32, split on the fly.
template <int AMODE>
__device__ void gemm_tile(const void* A0, const void* A1,
                          const u16* __restrict__ Bh, const u16* __restrict__ Bl,
                          float* __restrict__ Cb, int M, int N, int K,
                          int lda, int ldb, int ldc,
                          int m0, int n0, int ks0, int kend,
                          const float* biasp, int act,
                          u16* d48h, u16* d48l, int ncap, int ldhl,
                          u16* LDSU) {
  u16* SA = LDSU;           // [buf][hl][4096] -> ((buf<<1)|hl)*4096
  u16* SB = LDSU + 16384;

  int tid = threadIdx.x;
  int r0 = tid >> 2, g0 = tid & 3;
  int r1 = r0 + 64;
  int l0 = lofs(r0, g0), l1 = lofs(r1, g0);
  const u16* Ahb = (const u16*)A0;
  const u16* Alb = (const u16*)A1;
  const float* Af = (const float*)A0;
  const float* Ag = (const float*)A1;
  const u16* Bhb = Bh;
  const u16* Blb = Bl;
  long aoff0 = (long)(m0 + r0) * lda, aoff1 = (long)(m0 + r1) * lda;
  long boff0 = (long)(n0 + r0) * ldb, boff1 = (long)(n0 + r1) * ldb;
  bool am0 = (m0 + r0) < M, am1 = (m0 + r1) < M;
  bool bm0 = (n0 + r0) < N, bm1 = (n0 + r1) < N;

  int lane = tid & 63, w = tid >> 6;
  int wr = w >> 1, wc = w & 1;
  int fr = lane & 15, kh = lane >> 4;
  int offA[4], offB[4];
#pragma unroll
  for (int i = 0; i < 4; ++i) {
    offA[i] = lofs(wr * 64 + i * 16 + fr, kh);
    offB[i] = lofs(wc * 64 + i * 16 + fr, kh);
  }

  uint4 a0h, a1h, a0l, a1l, b0h, b1h, b0l, b1l;
  auto loadA = [&](long rowoff, bool ok, int k_, uint4& hh, uint4& ll) {
    uint4 z4 = {0, 0, 0, 0};
    if (AMODE == 0) {
      hh = ok ? *(const uint4*)(Ahb + rowoff + k_) : z4;
      ll = ok ? *(const uint4*)(Alb + rowoff + k_) : z4;
    } else {
      if (!ok) { hh = z4; ll = z4; return; }
      float4 f0 = *(const float4*)(Af + rowoff + k_);
      float4 f1 = *(const float4*)(Af + rowoff + k_ + 4);
      float4 g0v = *(const float4*)(Ag + rowoff + k_);
      float4 g1v = *(const float4*)(Ag + rowoff + k_ + 4);
      u16 ha[8], la[8];
      split2(0.5f * (f0.x + g0v.x), ha[0], la[0]);
      split2(0.5f * (f0.y + g0v.y), ha[1], la[1]);
      split2(0.5f * (f0.z + g0v.z), ha[2], la[2]);
      split2(0.5f * (f0.w + g0v.w), ha[3], la[3]);
      split2(0.5f * (f1.x + g1v.x), ha[4], la[4]);
      split2(0.5f * (f1.y + g1v.y), ha[5], la[5]);
      split2(0.5f * (f1.z + g1v.z), ha[6], la[6]);
      split2(0.5f * (f1.w + g1v.w), ha[7], la[7]);
      hh = *(const uint4*)ha;
      ll = *(const uint4*)la;
    }
  };
  auto loadstep = [&](int kb) {
    int k_ = kb + g0 * 8;
    bool kk = (k_ + 8 <= kend);
    uint4 z4 = {0, 0, 0, 0};
    loadA(aoff0, kk && am0, k_, a0h, a0l);
    loadA(aoff1, kk && am1, k_, a1h, a1l);
    b0h = (kk && bm0) ? *(const uint4*)(Bhb + boff0 + k_) : z4;
    b1h = (kk && bm1) ? *(const uint4*)(Bhb + boff1 + k_) : z4;
    b0l = (kk && bm0) ? *(const uint4*)(Blb + boff0 + k_) : z4;
    b1l = (kk && bm1) ? *(const uint4*)(Blb + boff1 + k_) : z4;
  };
  auto writebuf = [&](int b) {
    *(uint4*)&SA[((b << 1) | 0) * 4096 + l0] = a0h;
    *(uint4*)&SA[((b << 1) | 0) * 4096 + l1] = a1h;
    *(uint4*)&SA[((b << 1) | 1) * 4096 + l0] = a0l;
    *(uint4*)&SA[((b << 1) | 1) * 4096 + l1] = a1l;
    *(uint4*)&SB[((b << 1) | 0) * 4096 + l0] = b0h;
    *(uint4*)&SB[((b << 1) | 0) * 4096 + l1] = b1h;
    *(uint4*)&SB[((b << 1) | 1) * 4096 + l0] = b0l;
    *(uint4*)&SB[((b << 1) | 1) * 4096 + l1] = b1l;
  };

  f32x4 acc[4][4] = {};
  int nst = (kend - ks0 + 31) >> 5;
  loadstep(ks0);
  writebuf(0);
  if (nst > 1) loadstep(ks0 + 32);
  __syncthreads();

  for (int s = 0; s < nst; ++s) {
    int b = s & 1;
    bf16x8 fah[4], fal[4], fbh[4], fbl[4];
#pragma unroll
    for (int i = 0; i < 4; ++i) {
      fah[i] = __builtin_bit_cast(bf16x8, *(const uint4*)&SA[((b << 1) | 0) * 4096 + offA[i]]);
      fal[i] = __builtin_bit_cast(bf16x8, *(const uint4*)&SA[((b << 1) | 1) * 4096 + offA[i]]);
      fbh[i] = __builtin_bit_cast(bf16x8, *(const uint4*)&SB[((b << 1) | 0) * 4096 + offB[i]]);
      fbl[i] = __builtin_bit_cast(bf16x8, *(const uint4*)&SB[((b << 1) | 1) * 4096 + offB[i]]);
    }
#pragma unroll
    for (int mi = 0; mi < 4; ++mi)
#pragma unroll
      for (int ni = 0; ni < 4; ++ni) {
        acc[mi][ni] = MFMA_BF16(fah[mi], fbh[ni], acc[mi][ni]);
        acc[mi][ni] = MFMA_BF16(fah[mi], fbl[ni], acc[mi][ni]);
        acc[mi][ni] = MFMA_BF16(fal[mi], fbh[ni], acc[mi][ni]);
      }
    if (s + 1 < nst) {
      writebuf(b ^ 1);
      if (s + 2 < nst) loadstep(ks0 + (s + 2) * 32);
    }
    __syncthreads();
  }

#pragma unroll
  for (int mi = 0; mi < 4; ++mi)
#pragma unroll
    for (int ni = 0; ni < 4; ++ni) {
      int n = n0 + wc * 64 + ni * 16 + fr;
      if (n >= N) continue;
      float bv = biasp ? biasp[n] : 0.f;
#pragma unroll
      for (int r = 0; r < 4; ++r) {
        int m = m0 + wr * 64 + mi * 16 + kh * 4 + r;
        if (m >= M) continue;
        float v = acc[mi][ni][r] + bv;
        if (act == 1) v = (v > 20.f) ? v : log1pf(__expf(v));
        Cb[(long)m * ldc + n] = v;
        if (d48h && n < ncap) {
          u16 hh, ll;
          split2(v, hh, ll);
          d48h[(long)m * ldhl + n] = hh;
          d48l[(long)m * ldhl + n] = ll;
        }
      }
    }
}

// ---------------- standalone pre-kernels ----------------
__global__ void wconvert_kernel(const float* __restrict__ src,
                                u16* __restrict__ hi, u16* __restrict__ lo,
                                long n4) {
  long i = (long)blockIdx.x * 256 + threadIdx.x;
  long stride = (long)gridDim.x * 256;
  for (; i < n4; i += stride) {
    float4 v = ((const float4*)src)[i];
    ushort4 h, l;
    split2(v.x, h.x, l.x);
    split2(v.y, h.y, l.y);
    split2(v.z, h.z, l.z);
    split2(v.w, h.w, l.w);
    ((ushort4*)hi)[i] = h;
    ((ushort4*)lo)[i] = l;
  }
}

__global__ void patch_embed_kernel(const float* __restrict__ x,
                                   const float* __restrict__ pw,
                                   const float* __restrict__ pb,
                                   const float* __restrict__ cls,
                                   const float* __restrict__ pos,
                                   float* __restrict__ hidden,
                                   float* __restrict__ residual) {
  int c = blockIdx.x * 256 + threadIdx.x;
  int s = blockIdx.y;
  if (c >= DM) return;
  float val;
  if (s == 256) {
    val = cls[c];
  } else {
    int p = s - (s > 256 ? 1 : 0);
    int gy = p >> 6, gx = p & 63;
    const float* xp = x + gy * 16 * 1024 + gx * 16;
    const float* wp = pw + c * 256;
    float acc = pb[c];
#pragma unroll 4
    for (int ky = 0; ky < 16; ++ky)
#pragma unroll
      for (int kx = 0; kx < 16; ++kx)
        acc += xp[ky * 1024 + kx] * wp[ky * 16 + kx];
    val = acc;
  }
  long idx = (long)s * DM + c;
  hidden[idx] = val + pos[idx];
  residual[idx] = 0.f;
}

// ---------------- the megakernel: 24 layers + head, cooperative grid sync ----------------
__global__ __launch_bounds__(256, 2) void mega(
    const float* __restrict__ conv_w, const float* __restrict__ conv_b,
    const float* __restrict__ dtproj_b, const float* __restrict__ A_log,
    const float* __restrict__ D_skip, const float* __restrict__ norm_w,
    const float* __restrict__ norm_f_w, const float* __restrict__ head_w,
    const float* __restrict__ head_b,
    float* residual, float* xz_p, float* xc, float* zs, float* dbl,
    float* dtb, float* yb, float* hid_p,
    u16* hn_h, u16* hn_l, u16* xc_h, u16* xc_l, u16* d48_h, u16* d48_l,
    const u16* wi_h, const u16* wi_l, const u16* wx_h, const u16* wx_l,
    const u16* wd_h, const u16* wd_l, const u16* wo_h, const u16* wo_l,
    float* out) {
  __shared__ __align__(16) u16 LDSU[32768];  // 64 KB
  cg::grid_group grid = cg::this_grid();
  const int bid = blockIdx.x;
  const int tid = threadIdx.x;
  const long PHN = (long)L_SEQ * DM;
  const long PZ = (long)L_SEQ * 2 * DI;
  const long LDIlen = (long)L_SEQ * DI;

  for (int l = 0; l < DEPTH; ++l) {
    const u16* wih = wi_h + (long)l * 2 * DI * DM;
    const u16* wil = wi_l + (long)l * 2 * DI * DM;
    const u16* wxh = wx_h + (long)l * 2 * 80 * DI;
    const u16* wxl = wx_l + (long)l * 2 * 80 * DI;
    const u16* wdh = wd_h + (long)l * 2 * DI * DTRANK;
    const u16* wdl = wd_l + (long)l * 2 * DI * DTRANK;
    const u16* woh = wo_h + (long)l * DM * DI;
    const u16* wol = wo_l + (long)l * DM * DI;
    const float* cw = conv_w + (long)l * 2 * DI * 4;
    const float* cb = conv_b + (long)l * 2 * DI;
    const float* db = dtproj_b + (long)l * 2 * DI;
    const float* Al = A_log + (long)l * 2 * DI * DSTATE;
    const float* Dk = D_skip + (long)l * 2 * DI;
    const float* nw = norm_w + (long)l * DM;
    int nparts = (l == 0) ? 1 : SKO;

    // ---- P1: residual += partials; hn = rmsnorm -> hi/lo ----
    for (int t = bid; t < L_SEQ; t += NBLK) {
      float* rrow = residual + (long)t * DM;
      float vals[3];
      float ss = 0.f;
#pragma unroll
      for (int i = 0; i < 3; ++i) {
        int c = tid + i * 256;
        float v = rrow[c];
        for (int p = 0; p < nparts; ++p) v += hid_p[(long)p * PHN + (long)t * DM + c];
        vals[i] = v;
        rrow[c] = v;
        ss += v * v;
      }
#pragma unroll
      for (int o = 32; o; o >>= 1) ss += __shfl_down(ss, o, 64);
      float* sacc = (float*)LDSU;
      if ((tid & 63) == 0) sacc[tid >> 6] = ss;
      __syncthreads();
      float tot = sacc[0] + sacc[1] + sacc[2] + sacc[3];
      float rs = rsqrtf(tot / (float)DM + 1e-5f);
      __syncthreads();
#pragma unroll
      for (int i = 0; i < 3; ++i) {
        int c = tid + i * 256;
        float y = vals[i] * rs * nw[c];
        u16 h, lo;
        split2(y, h, lo);
        hn_h[(long)t * DM + c] = h;
        hn_l[(long)t * DM + c] = lo;
      }
    }
    grid.sync();

    // ---- P2: in_proj, split-K=2: 24 x 5 x 2 = 240 tiles ----
    for (int vt = bid; vt < 24 * 5 * SKI; vt += NBLK) {
      int sk = vt & (SKI - 1), rest = vt >> 1;
      int my = rest / 24, nx = rest % 24;
      gemm_tile<0>(hn_h, hn_l, wih, wil, xz_p + (long)sk * PZ,
                   L_SEQ, 2 * DI, DM, DM, DM, 2 * DI,
                   my * 128, nx * 128, sk * 384, min(DM, sk * 384 + 384),
                   nullptr, 0, nullptr, nullptr, 0, 0, LDSU);
    }
    grid.sync();

    // ---- P3: conv+silu -> xc (+hi/lo); silu(z) -> zs ----
    for (int v = bid; v < 2310; v += NBLK) {
      if (v < 1540) {
        int dir = v / 770, vv = v - dir * 770;
        int idx = vv * 256 + tid;
        if (idx < L_SEQ * (DI / 4)) {
          int d4 = idx % (DI / 4);
          int t = idx / (DI / 4);
          int d = d4 * 4;
          float wv[4][4];
#pragma unroll
          for (int j = 0; j < 4; ++j) {
            float4 wr4 = *(const float4*)(cw + ((long)dir * DI + d + j) * 4);
            wv[j][0] = wr4.x; wv[j][1] = wr4.y; wv[j][2] = wr4.z; wv[j][3] = wr4.w;
          }
          float4 bv = *(const float4*)(cb + (long)dir * DI + d);
          float a0 = bv.x, a1 = bv.y, a2 = bv.z, a3 = bv.w;
#pragma unroll
          for (int k = 0; k < 4; ++k) {
            int tau = t + k - 3;
            if (tau >= 0) {
              int tsrc = dir ? (L_SEQ - 1 - tau) : tau;
              long o = (long)tsrc * (2 * DI) + d;
              float4 x0 = *(const float4*)(xz_p + o);
              float4 x1 = *(const float4*)(xz_p + o + PZ);
              a0 += wv[0][k] * (x0.x + x1.x);
              a1 += wv[1][k] * (x0.y + x1.y);
              a2 += wv[2][k] * (x0.z + x1.z);
              a3 += wv[3][k] * (x0.w + x1.w);
            }
          }
          float4 sv;
          sv.x = siluf(a0); sv.y = siluf(a1); sv.z = siluf(a2); sv.w = siluf(a3);
          long o = ((long)dir * L_SEQ + t) * DI + d;
          *(float4*)(xc + o) = sv;
          ushort4 h, lo;
          split2(sv.x, h.x, lo.x);
          split2(sv.y, h.y, lo.y);
          split2(sv.z, h.z, lo.z);
          split2(sv.w, h.w, lo.w);
          *(ushort4*)(xc_h + o) = h;
          *(ushort4*)(xc_l + o) = lo;
        }
      } else {
        int vv = v - 1540;
        int idx = vv * 256 + tid;
        if (idx < L_SEQ * (DI / 4)) {
          int d4 = idx % (DI / 4);
          int t = idx / (DI / 4);
          long zo = (long)t * (2 * DI) + DI + d4 * 4;
          float4 z0 = *(const float4*)(xz_p + zo);
          float4 z1 = *(const float4*)(xz_p + zo + PZ);
          float4 sv;
          sv.x = siluf(z0.x + z1.x);
          sv.y = siluf(z0.y + z1.y);
          sv.z = siluf(z0.z + z1.z);
          sv.w = siluf(z0.w + z1.w);
          *(float4*)(zs + (long)t * DI + d4 * 4) = sv;
        }
      }
    }
    grid.sync();

    // ---- P4: x_proj (10 tiles): dbl fp32 + d48 hi/lo ----
    if (bid < 10) {
      int dir = bid / 5, my = bid % 5;
      gemm_tile<0>(xc_h + dir * LDIlen, xc_l + dir * LDIlen,
                   wxh + (long)dir * 80 * DI, wxl + (long)dir * 80 * DI,
                   dbl + (long)dir * L_SEQ * 80,
                   L_SEQ, 80, DI, DI, DI, 80,
                   my * 128, 0, 0, DI,
                   nullptr, 0,
                   d48_h + (long)dir * L_SEQ * DTRANK,
                   d48_l + (long)dir * L_SEQ * DTRANK, DTRANK, DTRANK, LDSU);
    }
    grid.sync();

    // ---- P5: dt_proj (12 x 5 x 2 = 120 tiles): softplus(d48 @ dw^T + db) ----
    for (int vt = bid; vt < 120; vt += NBLK) {
      int dir = vt / 60, r = vt - dir * 60;
      int my = r / 12, nx = r % 12;
      gemm_tile<0>(d48_h + (long)dir * L_SEQ * DTRANK, d48_l + (long)dir * L_SEQ * DTRANK,
                   wdh + (long)dir * DI * DTRANK, wdl + (long)dir * DI * DTRANK,
                   dtb + dir * LDIlen,
                   L_SEQ, DI, DTRANK, DTRANK, DTRANK, DI,
                   my * 128, nx * 128, 0, DTRANK,
                   db + dir * DI, 1, nullptr, nullptr, 0, 0, LDSU);
    }
    grid.sync();

    // ---- P6: chunked scan (block-local fixup) ----
    for (int vb = bid; vb < 384; vb += NBLK) {
      int dir = vb / 192, d0 = (vb - dir * 192) * 8;
      float* Q = (float*)LDSU;              // [8][NC][16]
      float* Sv = (float*)LDSU + 4096;      // [8][NC]
      const float* dtp = dtb + dir * LDIlen;
      const float* xcp = xc + dir * LDIlen;
      const float* dblp = dbl + (long)dir * L_SEQ * 80;
      int dl = tid & 7, c = tid >> 3;
      int d = d0 + dl;
      float negA[DSTATE];
#pragma unroll
      for (int n = 0; n < DSTATE; ++n)
        negA[n] = -__expf(Al[((long)dir * DI + d) * DSTATE + n]);
      int t0 = c * CLEN, t1 = min(t0 + CLEN, L_SEQ);
      {
        float h[DSTATE];
#pragma unroll
        for (int n = 0; n < DSTATE; ++n) h[n] = 0.f;
        float S = 0.f;
        for (int t = t0; t < t1; ++t) {
          float dt = dtp[(long)t * DI + d];
          float u = xcp[(long)t * DI + d];
          float du = dt * u;
          S += dt;
          const float4* B4 = (const float4*)(dblp + (long)t * 80 + DTRANK);
          float4 b0 = B4[0], b1 = B4[1], b2 = B4[2], b3 = B4[3];
          float Bv[DSTATE] = {b0.x, b0.y, b0.z, b0.w, b1.x, b1.y, b1.z, b1.w,
                              b2.x, b2.y, b2.z, b2.w, b3.x, b3.y, b3.z, b3.w};
#pragma unroll
          for (int n = 0; n < DSTATE; ++n)
            h[n] = h[n] * __expf(dt * negA[n]) + du * Bv[n];
        }
        Sv[dl * NC + c] = S;
#pragma unroll
        for (int n = 0; n < DSTATE; ++n) Q[(dl * NC + c) * DSTATE + n] = h[n];
      }
      __syncthreads();
      if (tid < 128) {
        int fdl = tid >> 4, n = tid & 15;
        int fd = d0 + fdl;
        float nA = -__expf(Al[((long)dir * DI + fd) * DSTATE + n]);
        float h = 0.f;
        for (int cc = 0; cc < NC; ++cc) {
          float S = Sv[fdl * NC + cc];
          float q = Q[(fdl * NC + cc) * DSTATE + n];
          Q[(fdl * NC + cc) * DSTATE + n] = h;
          h = h * __expf(nA * S) + q;
        }
      }
      __syncthreads();
      {
        float h[DSTATE];
#pragma unroll
        for (int n = 0; n < DSTATE; ++n) h[n] = Q[(dl * NC + c) * DSTATE + n];
        float dskip = Dk[(long)dir * DI + d];
        for (int t = t0; t < t1; ++t) {
          float dt = dtp[(long)t * DI + d];
          float u = xcp[(long)t * DI + d];
          float du = dt * u;
          const float4* B4 = (const float4*)(dblp + (long)t * 80 + DTRANK);
          float4 b0 = B4[0], b1 = B4[1], b2 = B4[2], b3 = B4[3];
          float4 c0 = B4[4], c1 = B4[5], c2 = B4[6], c3 = B4[7];
          float Bv[DSTATE] = {b0.x, b0.y, b0.z, b0.w, b1.x, b1.y, b1.z, b1.w,
                              b2.x, b2.y, b2.z, b2.w, b3.x, b3.y, b3.z, b3.w};
          float Cv[DSTATE] = {c0.x, c0.y, c0.z, c0.w, c1.x, c1.y, c1.z, c1.w,
                              c2.x, c2.y, c2.z, c2.w, c3.x, c3.y, c3.z, c3.w};
          float acc = 0.f;
#pragma unroll
          for (int n = 0; n < DSTATE; ++n) {
            h[n] = h[n] * __expf(dt * negA[n]) + du * Bv[n];
            acc += h[n] * Cv[n];
          }
          int tsrc = dir ? (L_SEQ - 1 - t) : t;
          float sz = zs[(long)tsrc * DI + d];
          yb[((long)dir * L_SEQ + tsrc) * DI + d] = (acc + dskip * u) * sz;
        }
      }
      __syncthreads();
    }
    grid.sync();

    // ---- P7: out_proj, fused yavg, split-K=8: 6 x 5 x 8 = 240 tiles ----
    for (int vt = bid; vt < 240; vt += NBLK) {
      int sk = vt & 7, rest = vt >> 3;
      int my = rest / 6, nx = rest % 6;
      gemm_tile<1>(yb, yb + LDIlen, woh, wol, hid_p + (long)sk * PHN,
                   L_SEQ, DM, DI, DI, DI, DM,
                   my * 128, nx * 128, sk * 192, sk * 192 + 192,
                   nullptr, 0, nullptr, nullptr, 0, 0, LDSU);
    }
    grid.sync();
  }

  // ---- head: final rmsnorm(token 256) + classifier ----
  for (int j = bid; j < NCLS; j += NBLK) {
    const float* r = residual + (long)256 * DM;
    float ss = 0.f, dp = 0.f;
#pragma unroll
    for (int i = 0; i < 3; ++i) {
      int c = tid + i * 256;
      float v = r[c];
      for (int p = 0; p < SKO; ++p) v += hid_p[(long)p * PHN + (long)256 * DM + c];
      ss += v * v;
      dp += v * norm_f_w[c] * head_w[(long)j * DM + c];
    }
#pragma unroll
    for (int o = 32; o; o >>= 1) {
      ss += __shfl_down(ss, o, 64);
      dp += __shfl_down(dp, o, 64);
    }
    float* s1 = (float*)LDSU;
    float* s2 = (float*)LDSU + 8;
    if ((tid & 63) == 0) {
      s1[tid >> 6] = ss;
      s2[tid >> 6] = dp;
    }
    __syncthreads();
    if (tid == 0) {
      float tot = s1[0] + s1[1] + s1[2] + s1[3];
      float dd = s2[0] + s2[1] + s2[2] + s2[3];
      out[j] = dd * rsqrtf(tot / (float)DM + 1e-5f) + head_b[j];
    }
    __syncthreads();
  }
}

extern "C" void kernel_launch(void* const* d_in, const int* in_sizes, int n_in,
                              void* d_out, int out_size, void* d_ws, size_t ws_size,
                              hipStream_t stream) {
  const float* x        = (const float*)d_in[0];
  const float* patch_w  = (const float*)d_in[1];
  const float* patch_b  = (const float*)d_in[2];
  const float* cls_tok  = (const float*)d_in[3];
  const float* pos_emb  = (const float*)d_in[4];
  const float* in_proj  = (const float*)d_in[5];
  const float* conv_w   = (const float*)d_in[6];
  const float* conv_b   = (const float*)d_in[7];
  const float* xproj_w  = (const float*)d_in[8];
  const float* dtproj_w = (const float*)d_in[9];
  const float* dtproj_b = (const float*)d_in[10];
  const float* A_log    = (const float*)d_in[11];
  const float* D_skip   = (const float*)d_in[12];
  const float* out_proj = (const float*)d_in[13];
  const float* norm_w   = (const float*)d_in[14];
  const float* norm_f_w = (const float*)d_in[15];
  const float* head_w   = (const float*)d_in[16];
  const float* head_b   = (const float*)d_in[17];
  float* out = (float*)d_out;

  const long PHN = (long)L_SEQ * DM;
  const long PZ  = (long)L_SEQ * 2 * DI;

  char* base = (char*)d_ws;
  float* fb = (float*)(base + 32768);
  float* residual = fb; fb += PHN;
  float* xz_p     = fb; fb += SKI * PZ;
  float* xc       = fb; fb += (long)2 * L_SEQ * DI;
  float* zs       = fb; fb += (long)L_SEQ * DI;
  float* dbl      = fb; fb += (long)2 * L_SEQ * 80;
  float* dtb      = fb; fb += (long)2 * L_SEQ * DI;
  float* yb       = fb; fb += (long)2 * L_SEQ * DI;
  float* hid_p    = fb; fb += (long)SKO * PHN;

  u16* wsu = (u16*)fb;
  const long N_HN = PHN;
  const long N_XC = (long)2 * L_SEQ * DI;
  const long N_D48 = (long)2 * L_SEQ * DTRANK;
  const long N_WI = (long)DEPTH * 2 * DI * DM;
  const long N_WX = (long)DEPTH * 2 * 80 * DI;
  const long N_WD = (long)DEPTH * 2 * DI * DTRANK;
  const long N_WO = (long)DEPTH * DM * DI;
  u16* hn_h = wsu; wsu += N_HN;
  u16* hn_l = wsu; wsu += N_HN;
  u16* xc_h = wsu; wsu += N_XC;
  u16* xc_l = wsu; wsu += N_XC;
  u16* d48_h = wsu; wsu += N_D48;
  u16* d48_l = wsu; wsu += N_D48;
  u16* wi_h = wsu; wsu += N_WI;
  u16* wi_l = wsu; wsu += N_WI;
  u16* wx_h = wsu; wsu += N_WX;
  u16* wx_l = wsu; wsu += N_WX;
  u16* wd_h = wsu; wsu += N_WD;
  u16* wd_l = wsu; wsu += N_WD;
  u16* wo_h = wsu; wsu += N_WO;
  u16* wo_l = wsu; wsu += N_WO;

  wconvert_kernel<<<2048, 256, 0, stream>>>(in_proj,  wi_h, wi_l, N_WI / 4);
  wconvert_kernel<<<512,  256, 0, stream>>>(xproj_w,  wx_h, wx_l, N_WX / 4);
  wconvert_kernel<<<512,  256, 0, stream>>>(dtproj_w, wd_h, wd_l, N_WD / 4);
  wconvert_kernel<<<2048, 256, 0, stream>>>(out_proj, wo_h, wo_l, N_WO / 4);

  patch_embed_kernel<<<dim3(3, L_SEQ), 256, 0, stream>>>(
      x, patch_w, patch_b, cls_tok, pos_emb, hid_p, residual);

  void* kargs[] = {
      (void*)&conv_w, (void*)&conv_b, (void*)&dtproj_b, (void*)&A_log,
      (void*)&D_skip, (void*)&norm_w, (void*)&norm_f_w, (void*)&head_w,
      (void*)&head_b,
      (void*)&residual, (void*)&xz_p, (void*)&xc, (void*)&zs, (void*)&dbl,
      (void*)&dtb, (void*)&yb, (void*)&hid_p,
      (void*)&hn_h, (void*)&hn_l, (void*)&xc_h, (void*)&xc_l,
      (void*)&d48_h, (void*)&d48_l,
      (void*)&wi_h, (void*)&wi_l, (void*)&wx_h, (void*)&wx_l,
      (void*)&wd_h, (void*)&wd_l, (void*)&wo_h, (void*)&wo_l,
      (void*)&out};
  (void)hipLaunchCooperativeKernel((void*)mega, dim3(NBLK), dim3(256),
                                   kargs, 0, stream);
}

// Round 11
// 5206.551 us; speedup vs baseline: 3.4938x; 1.9991x over previous
//
#include <hip/hip_runtime.h>

#define L_SEQ 513
#define DM 768
#define DI 1536
#define DSTATE 16
#define DTRANK 48
#define NCLS 527
#define DEPTH 24
#define NC 32
#define CLEN 17
#define SKI 2     // split-K for in_proj (768 = 2*384)
#define SKO 8     // split-K for out_proj (1536 = 8*192)

typedef unsigned short u16;
typedef unsigned int u32;
typedef __bf16 bf16x8 __attribute__((ext_vector_type(8)));
typedef float f32x4 __attribute__((ext_vector_type(4)));

#define MFMA_BF16(A, B, C) __builtin_amdgcn_mfma_f32_16x16x32_bf16(A, B, C, 0, 0, 0)

__device__ inline u16 f2bf(float x) {
  unsigned u = __float_as_uint(x);
  return (u16)((u + 0x7FFFu + ((u >> 16) & 1u)) >> 16);
}
__device__ inline float bf2f(u16 h) { return __uint_as_float((unsigned)h << 16); }
__device__ inline void split2(float v, u16& h, u16& l) {
  h = f2bf(v);
  l = f2bf(v - bf2f(h));
}
__device__ __forceinline__ int lofs(int row, int g) {
  int swz = (row & 3) ^ ((row >> 2) & 3);
  return row * 32 + ((g ^ swz) << 3);
}
__device__ inline float siluf(float v) { return v / (1.f + __expf(-v)); }

// ---------------- 128x128 bf16 hi/lo MFMA GEMM, split-K, epilogues ----------------
// AMODE 0: A pre-split u16 hi/lo. AMODE 1: A = 0.5*(A0+A1) fp32, split on the fly.
template <int AMODE>
__global__ __launch_bounds__(256) void gemm128(
    const void* A0, const void* A1,
    const u16* __restrict__ Bh, const u16* __restrict__ Bl,
    float* __restrict__ C,
    int M, int N, int K, int lda, int ldb, int ldc,
    long sA, long sB, long sC, int NSK, int Kb, long sP,
    const float* __restrict__ bias, long sBias, int act,
    u16* __restrict__ Chi, u16* __restrict__ Clo, int ncap, int ldhl, long sChl) {
  __shared__ __align__(16) u16 LDSU[32768];  // 64 KB
  u16* SA = LDSU;
  u16* SB = LDSU + 16384;

  int z = blockIdx.z;
  int batch = z / NSK, sk = z - batch * NSK;
  const u16* Ahb = (const u16*)A0 + (AMODE == 0 ? (long)batch * sA : 0);
  const u16* Alb = (const u16*)A1 + (AMODE == 0 ? (long)batch * sA : 0);
  const float* Af = (const float*)A0 + (AMODE == 1 ? (long)batch * sA : 0);
  const float* Ag = (const float*)A1 + (AMODE == 1 ? (long)batch * sA : 0);
  const u16* Bhb = Bh + (long)batch * sB;
  const u16* Blb = Bl + (long)batch * sB;
  float* Cb = C + (long)batch * sC + (long)sk * sP;
  const float* biasb = bias ? bias + (long)batch * sBias : nullptr;
  u16* Chib = Chi ? Chi + (long)batch * sChl : nullptr;
  u16* Clob = Clo ? Clo + (long)batch * sChl : nullptr;
  int ks0 = sk * Kb;
  int kend = min(ks0 + Kb, K);

  int tid = threadIdx.x;
  int m0 = blockIdx.y * 128, n0 = blockIdx.x * 128;

  int r0 = tid >> 2, g0 = tid & 3;
  int r1 = r0 + 64;
  int l0 = lofs(r0, g0), l1 = lofs(r1, g0);
  long aoff0 = (long)(m0 + r0) * lda, aoff1 = (long)(m0 + r1) * lda;
  long boff0 = (long)(n0 + r0) * ldb, boff1 = (long)(n0 + r1) * ldb;
  bool am0 = (m0 + r0) < M, am1 = (m0 + r1) < M;
  bool bm0 = (n0 + r0) < N, bm1 = (n0 + r1) < N;

  int lane = tid & 63, w = tid >> 6;
  int wr = w >> 1, wc = w & 1;
  int fr = lane & 15, kh = lane >> 4;
  int offA[4], offB[4];
#pragma unroll
  for (int i = 0; i < 4; ++i) {
    offA[i] = lofs(wr * 64 + i * 16 + fr, kh);
    offB[i] = lofs(wc * 64 + i * 16 + fr, kh);
  }

  uint4 a0h, a1h, a0l, a1l, b0h, b1h, b0l, b1l;
  auto loadA = [&](long rowoff, bool ok, int k_, uint4& hh, uint4& ll) {
    uint4 z4 = {0, 0, 0, 0};
    if (AMODE == 0) {
      hh = ok ? *(const uint4*)(Ahb + rowoff + k_) : z4;
      ll = ok ? *(const uint4*)(Alb + rowoff + k_) : z4;
    } else {
      if (!ok) { hh = z4; ll = z4; return; }
      float4 f0 = *(const float4*)(Af + rowoff + k_);
      float4 f1 = *(const float4*)(Af + rowoff + k_ + 4);
      float4 g0v = *(const float4*)(Ag + rowoff + k_);
      float4 g1v = *(const float4*)(Ag + rowoff + k_ + 4);
      u16 ha[8], la[8];
      split2(0.5f * (f0.x + g0v.x), ha[0], la[0]);
      split2(0.5f * (f0.y + g0v.y), ha[1], la[1]);
      split2(0.5f * (f0.z + g0v.z), ha[2], la[2]);
      split2(0.5f * (f0.w + g0v.w), ha[3], la[3]);
      split2(0.5f * (f1.x + g1v.x), ha[4], la[4]);
      split2(0.5f * (f1.y + g1v.y), ha[5], la[5]);
      split2(0.5f * (f1.z + g1v.z), ha[6], la[6]);
      split2(0.5f * (f1.w + g1v.w), ha[7], la[7]);
      hh = *(const uint4*)ha;
      ll = *(const uint4*)la;
    }
  };
  auto loadstep = [&](int kb) {
    int k_ = kb + g0 * 8;
    bool kk = (k_ + 8 <= kend);
    uint4 z4 = {0, 0, 0, 0};
    loadA(aoff0, kk && am0, k_, a0h, a0l);
    loadA(aoff1, kk && am1, k_, a1h, a1l);
    b0h = (kk && bm0) ? *(const uint4*)(Bhb + boff0 + k_) : z4;
    b1h = (kk && bm1) ? *(const uint4*)(Bhb + boff1 + k_) : z4;
    b0l = (kk && bm0) ? *(const uint4*)(Blb + boff0 + k_) : z4;
    b1l = (kk && bm1) ? *(const uint4*)(Blb + boff1 + k_) : z4;
  };
  auto writebuf = [&](int b) {
    *(uint4*)&SA[((b << 1) | 0) * 4096 + l0] = a0h;
    *(uint4*)&SA[((b << 1) | 0) * 4096 + l1] = a1h;
    *(uint4*)&SA[((b << 1) | 1) * 4096 + l0] = a0l;
    *(uint4*)&SA[((b << 1) | 1) * 4096 + l1] = a1l;
    *(uint4*)&SB[((b << 1) | 0) * 4096 + l0] = b0h;
    *(uint4*)&SB[((b << 1) | 0) * 4096 + l1] = b1h;
    *(uint4*)&SB[((b << 1) | 1) * 4096 + l0] = b0l;
    *(uint4*)&SB[((b << 1) | 1) * 4096 + l1] = b1l;
  };

  f32x4 acc[4][4] = {};
  int nst = (kend - ks0 + 31) >> 5;
  loadstep(ks0);
  writebuf(0);
  if (nst > 1) loadstep(ks0 + 32);
  __syncthreads();

  for (int s = 0; s < nst; ++s) {
    int b = s & 1;
    bf16x8 fah[4], fal[4], fbh[4], fbl[4];
#pragma unroll
    for (int i = 0; i < 4; ++i) {
      fah[i] = __builtin_bit_cast(bf16x8, *(const uint4*)&SA[((b << 1) | 0) * 4096 + offA[i]]);
      fal[i] = __builtin_bit_cast(bf16x8, *(const uint4*)&SA[((b << 1) | 1) * 4096 + offA[i]]);
      fbh[i] = __builtin_bit_cast(bf16x8, *(const uint4*)&SB[((b << 1) | 0) * 4096 + offB[i]]);
      fbl[i] = __builtin_bit_cast(bf16x8, *(const uint4*)&SB[((b << 1) | 1) * 4096 + offB[i]]);
    }
#pragma unroll
    for (int mi = 0; mi < 4; ++mi)
#pragma unroll
      for (int ni = 0; ni < 4; ++ni) {
        acc[mi][ni] = MFMA_BF16(fah[mi], fbh[ni], acc[mi][ni]);
        acc[mi][ni] = MFMA_BF16(fah[mi], fbl[ni], acc[mi][ni]);
        acc[mi][ni] = MFMA_BF16(fal[mi], fbh[ni], acc[mi][ni]);
      }
    if (s + 1 < nst) {
      writebuf(b ^ 1);
      if (s + 2 < nst) loadstep(ks0 + (s + 2) * 32);
    }
    __syncthreads();
  }

#pragma unroll
  for (int mi = 0; mi < 4; ++mi)
#pragma unroll
    for (int ni = 0; ni < 4; ++ni) {
      int n = n0 + wc * 64 + ni * 16 + fr;
      if (n >= N) continue;
      float bv = biasb ? biasb[n] : 0.f;
#pragma unroll
      for (int r = 0; r < 4; ++r) {
        int m = m0 + wr * 64 + mi * 16 + kh * 4 + r;
        if (m >= M) continue;
        float v = acc[mi][ni][r] + bv;
        if (act == 1) v = (v > 20.f) ? v : log1pf(__expf(v));
        Cb[(long)m * ldc + n] = v;
        if (Chib && n < ncap) {
          u16 hh, ll;
          split2(v, hh, ll);
          Chib[(long)m * ldhl + n] = hh;
          Clob[(long)m * ldhl + n] = ll;
        }
      }
    }
}

// ---------------- weight fp32 -> bf16 hi/lo splitter ----------------
__global__ void wconvert_kernel(const float* __restrict__ src,
                                u16* __restrict__ hi, u16* __restrict__ lo,
                                long n4) {
  long i = (long)blockIdx.x * 256 + threadIdx.x;
  long stride = (long)gridDim.x * 256;
  for (; i < n4; i += stride) {
    float4 v = ((const float4*)src)[i];
    ushort4 h, l;
    split2(v.x, h.x, l.x);
    split2(v.y, h.y, l.y);
    split2(v.z, h.z, l.z);
    split2(v.w, h.w, l.w);
    ((ushort4*)hi)[i] = h;
    ((ushort4*)lo)[i] = l;
  }
}

// ---------------- patch embed + cls insert + pos add ----------------
__global__ void patch_embed_kernel(const float* __restrict__ x,
                                   const float* __restrict__ pw,
                                   const float* __restrict__ pb,
                                   const float* __restrict__ cls,
                                   const float* __restrict__ pos,
                                   float* __restrict__ hidden,
                                   float* __restrict__ residual) {
  int c = blockIdx.x * 256 + threadIdx.x;
  int s = blockIdx.y;
  if (c >= DM) return;
  float val;
  if (s == 256) {
    val = cls[c];
  } else {
    int p = s - (s > 256 ? 1 : 0);
    int gy = p >> 6, gx = p & 63;
    const float* xp = x + gy * 16 * 1024 + gx * 16;
    const float* wp = pw + c * 256;
    float acc = pb[c];
#pragma unroll 4
    for (int ky = 0; ky < 16; ++ky)
#pragma unroll
      for (int kx = 0; kx < 16; ++kx)
        acc += xp[ky * 1024 + kx] * wp[ky * 16 + kx];
    val = acc;
  }
  long idx = (long)s * DM + c;
  hidden[idx] = val + pos[idx];
  residual[idx] = 0.f;
}

// ---- residual += sum(hidden partials); hn = rmsnorm(residual)*w -> bf16 hi/lo ----
__global__ void rmsnorm_kernel(const float* __restrict__ hp, int nparts, long pstr,
                               float* __restrict__ residual,
                               u16* __restrict__ hnh, u16* __restrict__ hnl,
                               const float* __restrict__ w) {
  int t = blockIdx.x;
  float* rrow = residual + (long)t * DM;
  int tid = threadIdx.x;
  float vals[3];
  float ss = 0.f;
#pragma unroll
  for (int i = 0; i < 3; ++i) {
    int c = tid + i * 256;
    float v = rrow[c];
    for (int p = 0; p < nparts; ++p) v += hp[(long)p * pstr + (long)t * DM + c];
    vals[i] = v;
    rrow[c] = v;
    ss += v * v;
  }
#pragma unroll
  for (int o = 32; o; o >>= 1) ss += __shfl_down(ss, o, 64);
  __shared__ float sacc[4];
  if ((tid & 63) == 0) sacc[tid >> 6] = ss;
  __syncthreads();
  float tot = sacc[0] + sacc[1] + sacc[2] + sacc[3];
  float rs = rsqrtf(tot / (float)DM + 1e-5f);
#pragma unroll
  for (int i = 0; i < 3; ++i) {
    int c = tid + i * 256;
    float y = vals[i] * rs * w[c];
    u16 h, l;
    split2(y, h, l);
    hnh[(long)t * DM + c] = h;
    hnl[(long)t * DM + c] = l;
  }
}

// ---- conv+silu (sums SKI partials) -> xc fp32 + hi/lo; plus silu(z) -> zs ----
__global__ void conv_zs_kernel(const float* __restrict__ xz_p,
                               const float* __restrict__ cw,
                               const float* __restrict__ cb,
                               float* __restrict__ xc,
                               u16* __restrict__ xch, u16* __restrict__ xcl,
                               float* __restrict__ zs) {
  const long PZ = (long)L_SEQ * 2 * DI;
  int v = blockIdx.x;
  int tid = threadIdx.x;
  if (v < 1540) {
    int dir = v / 770, vv = v - dir * 770;
    int idx = vv * 256 + tid;
    if (idx >= L_SEQ * (DI / 4)) return;
    int d4 = idx % (DI / 4);
    int t = idx / (DI / 4);
    int d = d4 * 4;
    float wv[4][4];
#pragma unroll
    for (int j = 0; j < 4; ++j) {
      float4 wr4 = *(const float4*)(cw + ((long)dir * DI + d + j) * 4);
      wv[j][0] = wr4.x; wv[j][1] = wr4.y; wv[j][2] = wr4.z; wv[j][3] = wr4.w;
    }
    float4 bv = *(const float4*)(cb + (long)dir * DI + d);
    float a0 = bv.x, a1 = bv.y, a2 = bv.z, a3 = bv.w;
#pragma unroll
    for (int k = 0; k < 4; ++k) {
      int tau = t + k - 3;
      if (tau >= 0) {
        int tsrc = dir ? (L_SEQ - 1 - tau) : tau;
        long o = (long)tsrc * (2 * DI) + d;
        float4 x0 = *(const float4*)(xz_p + o);
        float4 x1 = *(const float4*)(xz_p + o + PZ);
        a0 += wv[0][k] * (x0.x + x1.x);
        a1 += wv[1][k] * (x0.y + x1.y);
        a2 += wv[2][k] * (x0.z + x1.z);
        a3 += wv[3][k] * (x0.w + x1.w);
      }
    }
    float4 sv;
    sv.x = siluf(a0); sv.y = siluf(a1); sv.z = siluf(a2); sv.w = siluf(a3);
    long o = ((long)dir * L_SEQ + t) * DI + d;
    *(float4*)(xc + o) = sv;
    ushort4 h, lo;
    split2(sv.x, h.x, lo.x);
    split2(sv.y, h.y, lo.y);
    split2(sv.z, h.z, lo.z);
    split2(sv.w, h.w, lo.w);
    *(ushort4*)(xch + o) = h;
    *(ushort4*)(xcl + o) = lo;
  } else {
    int vv = v - 1540;
    int idx = vv * 256 + tid;
    if (idx >= L_SEQ * (DI / 4)) return;
    int d4 = idx % (DI / 4);
    int t = idx / (DI / 4);
    long zo = (long)t * (2 * DI) + DI + d4 * 4;
    float4 z0 = *(const float4*)(xz_p + zo);
    float4 z1 = *(const float4*)(xz_p + zo + PZ);
    float4 sv;
    sv.x = siluf(z0.x + z1.x);
    sv.y = siluf(z0.y + z1.y);
    sv.z = siluf(z0.z + z1.z);
    sv.w = siluf(z0.w + z1.w);
    *(float4*)(zs + (long)t * DI + d4 * 4) = sv;
  }
}

// ---------------- fused chunked scan (pass1 + LDS fixup + pass2) ----------------
__global__ __launch_bounds__(256) void scan_all(
    const float* __restrict__ dtb,   // (2,L,DI) softplus'ed
    const float* __restrict__ xc,    // (2,L,DI)
    const float* __restrict__ dbl,   // (2,L,80)
    const float* __restrict__ zs,    // (L,DI)
    const float* __restrict__ A_log,
    const float* __restrict__ Dsk,
    float* __restrict__ y) {
  __shared__ float Q[8 * NC * DSTATE];  // 16 KB
  __shared__ float Sv[8 * NC];
  const long LDIlen = (long)L_SEQ * DI;
  int dir = blockIdx.y;
  int d0 = blockIdx.x * 8;
  int tid = threadIdx.x;
  const float* dtp = dtb + dir * LDIlen;
  const float* xcp = xc + dir * LDIlen;
  const float* dblp = dbl + (long)dir * L_SEQ * 80;
  int dl = tid & 7, c = tid >> 3;
  int d = d0 + dl;
  float negA[DSTATE];
#pragma unroll
  for (int n = 0; n < DSTATE; ++n)
    negA[n] = -__expf(A_log[((long)dir * DI + d) * DSTATE + n]);
  int t0 = c * CLEN, t1 = min(t0 + CLEN, L_SEQ);
  {
    float h[DSTATE];
#pragma unroll
    for (int n = 0; n < DSTATE; ++n) h[n] = 0.f;
    float S = 0.f;
    for (int t = t0; t < t1; ++t) {
      float dt = dtp[(long)t * DI + d];
      float u = xcp[(long)t * DI + d];
      float du = dt * u;
      S += dt;
      const float4* B4 = (const float4*)(dblp + (long)t * 80 + DTRANK);
      float4 b0 = B4[0], b1 = B4[1], b2 = B4[2], b3 = B4[3];
      float Bv[DSTATE] = {b0.x, b0.y, b0.z, b0.w, b1.x, b1.y, b1.z, b1.w,
                          b2.x, b2.y, b2.z, b2.w, b3.x, b3.y, b3.z, b3.w};
#pragma unroll
      for (int n = 0; n < DSTATE; ++n)
        h[n] = h[n] * __expf(dt * negA[n]) + du * Bv[n];
    }
    Sv[dl * NC + c] = S;
#pragma unroll
    for (int n = 0; n < DSTATE; ++n) Q[(dl * NC + c) * DSTATE + n] = h[n];
  }
  __syncthreads();
  if (tid < 128) {
    int fdl = tid >> 4, n = tid & 15;
    int fd = d0 + fdl;
    float nA = -__expf(A_log[((long)dir * DI + fd) * DSTATE + n]);
    float h = 0.f;
    for (int cc = 0; cc < NC; ++cc) {
      float S = Sv[fdl * NC + cc];
      float q = Q[(fdl * NC + cc) * DSTATE + n];
      Q[(fdl * NC + cc) * DSTATE + n] = h;
      h = h * __expf(nA * S) + q;
    }
  }
  __syncthreads();
  {
    float h[DSTATE];
#pragma unroll
    for (int n = 0; n < DSTATE; ++n) h[n] = Q[(dl * NC + c) * DSTATE + n];
    float dskip = Dsk[(long)dir * DI + d];
    for (int t = t0; t < t1; ++t) {
      float dt = dtp[(long)t * DI + d];
      float u = xcp[(long)t * DI + d];
      float du = dt * u;
      const float4* B4 = (const float4*)(dblp + (long)t * 80 + DTRANK);
      float4 b0 = B4[0], b1 = B4[1], b2 = B4[2], b3 = B4[3];
      float4 c0 = B4[4], c1 = B4[5], c2 = B4[6], c3 = B4[7];
      float Bv[DSTATE] = {b0.x, b0.y, b0.z, b0.w, b1.x, b1.y, b1.z, b1.w,
                          b2.x, b2.y, b2.z, b2.w, b3.x, b3.y, b3.z, b3.w};
      float Cv[DSTATE] = {c0.x, c0.y, c0.z, c0.w, c1.x, c1.y, c1.z, c1.w,
                          c2.x, c2.y, c2.z, c2.w, c3.x, c3.y, c3.z, c3.w};
      float acc = 0.f;
#pragma unroll
      for (int n = 0; n < DSTATE; ++n) {
        h[n] = h[n] * __expf(dt * negA[n]) + du * Bv[n];
        acc += h[n] * Cv[n];
      }
      int tsrc = dir ? (L_SEQ - 1 - t) : t;
      float sz = zs[(long)tsrc * DI + d];
      y[((long)dir * L_SEQ + tsrc) * DI + d] = (acc + dskip * u) * sz;
    }
  }
}

// ---------------- final rmsnorm(token 256) + head (sums SKO partials) ----------------
__global__ void head_kernel(const float* __restrict__ residual,
                            const float* __restrict__ hp, long pstr,
                            const float* __restrict__ nfw,
                            const float* __restrict__ hw,
                            const float* __restrict__ hb,
                            float* __restrict__ out) {
  int j = blockIdx.x;
  int tid = threadIdx.x;
  const float* r = residual + (long)256 * DM;
  float ss = 0.f, dp = 0.f;
#pragma unroll
  for (int i = 0; i < 3; ++i) {
    int c = tid + i * 256;
    float v = r[c];
    for (int p = 0; p < SKO; ++p) v += hp[(long)p * pstr + (long)256 * DM + c];
    ss += v * v;
    dp += v * nfw[c] * hw[(long)j * DM + c];
  }
#pragma unroll
  for (int o = 32; o; o >>= 1) {
    ss += __shfl_down(ss, o, 64);
    dp += __shfl_down(dp, o, 64);
  }
  __shared__ float s1[4], s2[4];
  if ((tid & 63) == 0) {
    s1[tid >> 6] = ss;
    s2[tid >> 6] = dp;
  }
  __syncthreads();
  if (tid == 0) {
    float tot = s1[0] + s1[1] + s1[2] + s1[3];
    float d = s2[0] + s2[1] + s2[2] + s2[3];
    out[j] = d * rsqrtf(tot / (float)DM + 1e-5f) + hb[j];
  }
}

extern "C" void kernel_launch(void* const* d_in, const int* in_sizes, int n_in,
                              void* d_out, int out_size, void* d_ws, size_t ws_size,
                              hipStream_t stream) {
  const float* x        = (const float*)d_in[0];
  const float* patch_w  = (const float*)d_in[1];
  const float* patch_b  = (const float*)d_in[2];
  const float* cls_tok  = (const float*)d_in[3];
  const float* pos_emb  = (const float*)d_in[4];
  const float* in_proj  = (const float*)d_in[5];
  const float* conv_w   = (const float*)d_in[6];
  const float* conv_b   = (const float*)d_in[7];
  const float* xproj_w  = (const float*)d_in[8];
  const float* dtproj_w = (const float*)d_in[9];
  const float* dtproj_b = (const float*)d_in[10];
  const float* A_log    = (const float*)d_in[11];
  const float* D_skip   = (const float*)d_in[12];
  const float* out_proj = (const float*)d_in[13];
  const float* norm_w   = (const float*)d_in[14];
  const float* norm_f_w = (const float*)d_in[15];
  const float* head_w   = (const float*)d_in[16];
  const float* head_b   = (const float*)d_in[17];
  float* out = (float*)d_out;

  const long PHN = (long)L_SEQ * DM;
  const long PZ  = (long)L_SEQ * 2 * DI;
  const long LDIlen = (long)L_SEQ * DI;

  float* fb = (float*)d_ws;
  float* residual = fb; fb += PHN;
  float* xz_p     = fb; fb += SKI * PZ;
  float* xc       = fb; fb += (long)2 * LDIlen;
  float* zs       = fb; fb += LDIlen;
  float* dbl      = fb; fb += (long)2 * L_SEQ * 80;
  float* dtb      = fb; fb += (long)2 * LDIlen;
  float* yb       = fb; fb += (long)2 * LDIlen;
  float* hid_p    = fb; fb += (long)SKO * PHN;

  u16* wsu = (u16*)fb;
  const long N_HN = PHN;
  const long N_XC = (long)2 * LDIlen;
  const long N_D48 = (long)2 * L_SEQ * DTRANK;
  const long N_WI = (long)DEPTH * 2 * DI * DM;
  const long N_WX = (long)DEPTH * 2 * 80 * DI;
  const long N_WD = (long)DEPTH * 2 * DI * DTRANK;
  const long N_WO = (long)DEPTH * DM * DI;
  u16* hn_h = wsu; wsu += N_HN;
  u16* hn_l = wsu; wsu += N_HN;
  u16* xc_h = wsu; wsu += N_XC;
  u16* xc_l = wsu; wsu += N_XC;
  u16* d48_h = wsu; wsu += N_D48;
  u16* d48_l = wsu; wsu += N_D48;
  u16* wi_h = wsu; wsu += N_WI;
  u16* wi_l = wsu; wsu += N_WI;
  u16* wx_h = wsu; wsu += N_WX;
  u16* wx_l = wsu; wsu += N_WX;
  u16* wd_h = wsu; wsu += N_WD;
  u16* wd_l = wsu; wsu += N_WD;
  u16* wo_h = wsu; wsu += N_WO;
  u16* wo_l = wsu; wsu += N_WO;

  wconvert_kernel<<<2048, 256, 0, stream>>>(in_proj,  wi_h, wi_l, N_WI / 4);
  wconvert_kernel<<<512,  256, 0, stream>>>(xproj_w,  wx_h, wx_l, N_WX / 4);
  wconvert_kernel<<<512,  256, 0, stream>>>(dtproj_w, wd_h, wd_l, N_WD / 4);
  wconvert_kernel<<<2048, 256, 0, stream>>>(out_proj, wo_h, wo_l, N_WO / 4);

  patch_embed_kernel<<<dim3(3, L_SEQ), 256, 0, stream>>>(
      x, patch_w, patch_b, cls_tok, pos_emb, hid_p, residual);

  for (int l = 0; l < DEPTH; ++l) {
    const u16* wih = wi_h + (long)l * 2 * DI * DM;
    const u16* wil = wi_l + (long)l * 2 * DI * DM;
    const u16* wxh = wx_h + (long)l * 2 * 80 * DI;
    const u16* wxl = wx_l + (long)l * 2 * 80 * DI;
    const u16* wdh = wd_h + (long)l * 2 * DI * DTRANK;
    const u16* wdl = wd_l + (long)l * 2 * DI * DTRANK;
    const u16* woh = wo_h + (long)l * DM * DI;
    const u16* wol = wo_l + (long)l * DM * DI;
    const float* cw = conv_w + (long)l * 2 * DI * 4;
    const float* cb = conv_b + (long)l * 2 * DI;
    const float* db = dtproj_b + (long)l * 2 * DI;
    const float* Al = A_log + (long)l * 2 * DI * DSTATE;
    const float* Dk = D_skip + (long)l * 2 * DI;
    const float* nw = norm_w + (long)l * DM;

    // 1. rmsnorm
    rmsnorm_kernel<<<L_SEQ, 256, 0, stream>>>(
        hid_p, (l == 0) ? 1 : SKO, PHN, residual, hn_h, hn_l, nw);

    // 2. in_proj, split-K=2 -> xz partials
    gemm128<0><<<dim3(24, 5, SKI), 256, 0, stream>>>(
        hn_h, hn_l, wih, wil, xz_p, L_SEQ, 2 * DI, DM, DM, DM, 2 * DI,
        0, 0, 0, SKI, DM / SKI, PZ,
        nullptr, 0, 0, nullptr, nullptr, 0, 0, 0);

    // 3. conv+silu -> xc (+hi/lo); silu(z) -> zs
    conv_zs_kernel<<<2310, 256, 0, stream>>>(xz_p, cw, cb, xc, xc_h, xc_l, zs);

    // 4. x_proj (un-split, K=1536) -> dbl fp32 + d48 hi/lo
    gemm128<0><<<dim3(1, 5, 2), 256, 0, stream>>>(
        xc_h, xc_l, wxh, wxl, dbl, L_SEQ, 80, DI, DI, DI, 80,
        LDIlen, (long)80 * DI, (long)L_SEQ * 80, 1, DI, 0,
        nullptr, 0, 0, d48_h, d48_l, DTRANK, DTRANK, (long)L_SEQ * DTRANK);

    // 5. dt_proj: dtb = softplus(d48 @ dw^T + db)
    gemm128<0><<<dim3(12, 5, 2), 256, 0, stream>>>(
        d48_h, d48_l, wdh, wdl, dtb, L_SEQ, DI, DTRANK, DTRANK, DTRANK, DI,
        (long)L_SEQ * DTRANK, (long)DI * DTRANK, LDIlen, 1, DTRANK, 0,
        db, DI, 1, nullptr, nullptr, 0, 0, 0);

    // 6. fused chunked scan
    scan_all<<<dim3(192, 2), 256, 0, stream>>>(dtb, xc, dbl, zs, Al, Dk, yb);

    // 7. out_proj, fused yavg (AMODE1), split-K=8 -> hid_p partials
    gemm128<1><<<dim3(6, 5, SKO), 256, 0, stream>>>(
        yb, yb + LDIlen, woh, wol, hid_p, L_SEQ, DM, DI, DI, DI, DM,
        0, 0, 0, SKO, DI / SKO, PHN,
        nullptr, 0, 0, nullptr, nullptr, 0, 0, 0);
  }

  head_kernel<<<NCLS, 256, 0, stream>>>(residual, hid_p, PHN,
                                        norm_f_w, head_w, head_b, out);
}

// Round 12
// 4213.533 us; speedup vs baseline: 4.3172x; 1.2357x over previous
//
#include <hip/hip_runtime.h>

#define L_SEQ 513
#define DM 768
#define DI 1536
#define DSTATE 16
#define DTRANK 48
#define NCLS 527
#define DEPTH 24
#define NC 32
#define CLEN 17
#define SKI 3     // split-K for in_proj (768 = 3*256)
#define SKX 8     // split-K for x_proj (1536 = 8*192)
#define SKO 8     // split-K for out_proj (1536 = 8*192)

typedef unsigned short u16;
typedef unsigned int u32;
typedef __bf16 bf16x8 __attribute__((ext_vector_type(8)));
typedef float f32x4 __attribute__((ext_vector_type(4)));

#define MFMA_BF16(A, B, C) __builtin_amdgcn_mfma_f32_16x16x32_bf16(A, B, C, 0, 0, 0)

__device__ inline u16 f2bf(float x) {
  unsigned u = __float_as_uint(x);
  return (u16)((u + 0x7FFFu + ((u >> 16) & 1u)) >> 16);
}
__device__ inline float bf2f(u16 h) { return __uint_as_float((unsigned)h << 16); }
__device__ inline void split2(float v, u16& h, u16& l) {
  h = f2bf(v);
  l = f2bf(v - bf2f(h));
}
__device__ __forceinline__ int lofs(int row, int g) {
  int swz = (row & 3) ^ ((row >> 2) & 3);
  return row * 32 + ((g ^ swz) << 3);
}
__device__ inline float siluf(float v) { return v / (1.f + __expf(-v)); }

// ---------------- 128x128 bf16 hi/lo MFMA GEMM, split-K, epilogues ----------------
// AMODE 0: A pre-split u16 hi/lo.
// AMODE 1: A = 0.5*(A0+A1) fp32, split on the fly.
// AMODE 2: A = sum of 8 fp32 partials (stride sP), split on the fly; the LAST
//          grid.x column of blocks instead reduces cols [48,80) of the partials
//          into bcOut (B/C for the scan).
template <int AMODE>
__global__ __launch_bounds__(256) void gemm128(
    const void* A0, const void* A1,
    const u16* __restrict__ Bh, const u16* __restrict__ Bl,
    float* __restrict__ C,
    int M, int N, int K, int lda, int ldb, int ldc,
    long sA, long sB, long sC, int NSK, int Kb, long sP,
    const float* __restrict__ bias, long sBias, int act,
    float* __restrict__ bcOut) {
  __shared__ __align__(16) u16 LDSU[32768];  // 64 KB
  u16* SA = LDSU;
  u16* SB = LDSU + 16384;

  int z = blockIdx.z;
  int batch = z / NSK, sk = z - batch * NSK;
  int tid = threadIdx.x;

  if (AMODE == 2 && blockIdx.x == gridDim.x - 1) {
    // B/C reduce: sum 8 partials, cols 48..79
    const float* src = (const float*)A0 + (long)batch * sA;
    float* dst = bcOut + (long)batch * L_SEQ * 80;
    int m0 = blockIdx.y * 128;
    for (int i = tid; i < 128 * 32; i += 256) {
      int mm = m0 + (i >> 5), j = 48 + (i & 31);
      if (mm < M) {
        float v = 0.f;
#pragma unroll
        for (int p = 0; p < 8; ++p) v += src[(long)p * sP + (long)mm * 80 + j];
        dst[(long)mm * 80 + j] = v;
      }
    }
    return;
  }

  const u16* Ahb = (const u16*)A0 + (AMODE == 0 ? (long)batch * sA : 0);
  const u16* Alb = (const u16*)A1 + (AMODE == 0 ? (long)batch * sA : 0);
  const float* Af = (const float*)A0 + (AMODE != 0 ? (long)batch * sA : 0);
  const float* Ag = (AMODE == 1) ? (const float*)A1 + (long)batch * sA : nullptr;
  const u16* Bhb = Bh + (long)batch * sB;
  const u16* Blb = Bl + (long)batch * sB;
  float* Cb = C + (long)batch * sC + (AMODE == 2 ? 0 : (long)sk * sP);
  const float* biasb = bias ? bias + (long)batch * sBias : nullptr;
  int ks0 = sk * Kb;
  int kend = min(ks0 + Kb, K);

  int m0 = blockIdx.y * 128, n0 = blockIdx.x * 128;

  int r0 = tid >> 2, g0 = tid & 3;
  int r1 = r0 + 64;
  int l0 = lofs(r0, g0), l1 = lofs(r1, g0);
  long aoff0 = (long)(m0 + r0) * lda, aoff1 = (long)(m0 + r1) * lda;
  long boff0 = (long)(n0 + r0) * ldb, boff1 = (long)(n0 + r1) * ldb;
  bool am0 = (m0 + r0) < M, am1 = (m0 + r1) < M;
  bool bm0 = (n0 + r0) < N, bm1 = (n0 + r1) < N;

  int lane = tid & 63, w = tid >> 6;
  int wr = w >> 1, wc = w & 1;
  int fr = lane & 15, kh = lane >> 4;
  int offA[4], offB[4];
#pragma unroll
  for (int i = 0; i < 4; ++i) {
    offA[i] = lofs(wr * 64 + i * 16 + fr, kh);
    offB[i] = lofs(wc * 64 + i * 16 + fr, kh);
  }

  uint4 a0h, a1h, a0l, a1l, b0h, b1h, b0l, b1l;
  auto loadA = [&](long rowoff, bool ok, int k_, uint4& hh, uint4& ll) {
    uint4 z4 = {0, 0, 0, 0};
    if (AMODE == 0) {
      hh = ok ? *(const uint4*)(Ahb + rowoff + k_) : z4;
      ll = ok ? *(const uint4*)(Alb + rowoff + k_) : z4;
    } else {
      if (!ok) { hh = z4; ll = z4; return; }
      float v8[8];
      if (AMODE == 1) {
        float4 f0 = *(const float4*)(Af + rowoff + k_);
        float4 f1 = *(const float4*)(Af + rowoff + k_ + 4);
        float4 g0v = *(const float4*)(Ag + rowoff + k_);
        float4 g1v = *(const float4*)(Ag + rowoff + k_ + 4);
        v8[0] = 0.5f * (f0.x + g0v.x); v8[1] = 0.5f * (f0.y + g0v.y);
        v8[2] = 0.5f * (f0.z + g0v.z); v8[3] = 0.5f * (f0.w + g0v.w);
        v8[4] = 0.5f * (f1.x + g1v.x); v8[5] = 0.5f * (f1.y + g1v.y);
        v8[6] = 0.5f * (f1.z + g1v.z); v8[7] = 0.5f * (f1.w + g1v.w);
      } else {  // AMODE 2: sum 8 partials (stride sP)
        float4 s0 = {0, 0, 0, 0}, s1 = {0, 0, 0, 0};
#pragma unroll
        for (int p = 0; p < 8; ++p) {
          float4 f0 = *(const float4*)(Af + (long)p * sP + rowoff + k_);
          float4 f1 = *(const float4*)(Af + (long)p * sP + rowoff + k_ + 4);
          s0.x += f0.x; s0.y += f0.y; s0.z += f0.z; s0.w += f0.w;
          s1.x += f1.x; s1.y += f1.y; s1.z += f1.z; s1.w += f1.w;
        }
        v8[0] = s0.x; v8[1] = s0.y; v8[2] = s0.z; v8[3] = s0.w;
        v8[4] = s1.x; v8[5] = s1.y; v8[6] = s1.z; v8[7] = s1.w;
      }
      u16 ha[8], la[8];
#pragma unroll
      for (int i = 0; i < 8; ++i) split2(v8[i], ha[i], la[i]);
      hh = *(const uint4*)ha;
      ll = *(const uint4*)la;
    }
  };
  auto loadstep = [&](int kb) {
    int k_ = kb + g0 * 8;
    bool kk = (k_ + 8 <= kend);
    uint4 z4 = {0, 0, 0, 0};
    loadA(aoff0, kk && am0, k_, a0h, a0l);
    loadA(aoff1, kk && am1, k_, a1h, a1l);
    b0h = (kk && bm0) ? *(const uint4*)(Bhb + boff0 + k_) : z4;
    b1h = (kk && bm1) ? *(const uint4*)(Bhb + boff1 + k_) : z4;
    b0l = (kk && bm0) ? *(const uint4*)(Blb + boff0 + k_) : z4;
    b1l = (kk && bm1) ? *(const uint4*)(Blb + boff1 + k_) : z4;
  };
  auto writebuf = [&](int b) {
    *(uint4*)&SA[((b << 1) | 0) * 4096 + l0] = a0h;
    *(uint4*)&SA[((b << 1) | 0) * 4096 + l1] = a1h;
    *(uint4*)&SA[((b << 1) | 1) * 4096 + l0] = a0l;
    *(uint4*)&SA[((b << 1) | 1) * 4096 + l1] = a1l;
    *(uint4*)&SB[((b << 1) | 0) * 4096 + l0] = b0h;
    *(uint4*)&SB[((b << 1) | 0) * 4096 + l1] = b1h;
    *(uint4*)&SB[((b << 1) | 1) * 4096 + l0] = b0l;
    *(uint4*)&SB[((b << 1) | 1) * 4096 + l1] = b1l;
  };

  f32x4 acc[4][4] = {};
  int nst = (kend - ks0 + 31) >> 5;
  loadstep(ks0);
  writebuf(0);
  if (nst > 1) loadstep(ks0 + 32);
  __syncthreads();

  for (int s = 0; s < nst; ++s) {
    int b = s & 1;
    bf16x8 fah[4], fal[4], fbh[4], fbl[4];
#pragma unroll
    for (int i = 0; i < 4; ++i) {
      fah[i] = __builtin_bit_cast(bf16x8, *(const uint4*)&SA[((b << 1) | 0) * 4096 + offA[i]]);
      fal[i] = __builtin_bit_cast(bf16x8, *(const uint4*)&SA[((b << 1) | 1) * 4096 + offA[i]]);
      fbh[i] = __builtin_bit_cast(bf16x8, *(const uint4*)&SB[((b << 1) | 0) * 4096 + offB[i]]);
      fbl[i] = __builtin_bit_cast(bf16x8, *(const uint4*)&SB[((b << 1) | 1) * 4096 + offB[i]]);
    }
#pragma unroll
    for (int mi = 0; mi < 4; ++mi)
#pragma unroll
      for (int ni = 0; ni < 4; ++ni) {
        acc[mi][ni] = MFMA_BF16(fah[mi], fbh[ni], acc[mi][ni]);
        acc[mi][ni] = MFMA_BF16(fah[mi], fbl[ni], acc[mi][ni]);
        acc[mi][ni] = MFMA_BF16(fal[mi], fbh[ni], acc[mi][ni]);
      }
    if (s + 1 < nst) {
      writebuf(b ^ 1);
      if (s + 2 < nst) loadstep(ks0 + (s + 2) * 32);
    }
    __syncthreads();
  }

#pragma unroll
  for (int mi = 0; mi < 4; ++mi)
#pragma unroll
    for (int ni = 0; ni < 4; ++ni) {
      int n = n0 + wc * 64 + ni * 16 + fr;
      if (n >= N) continue;
      float bv = biasb ? biasb[n] : 0.f;
#pragma unroll
      for (int r = 0; r < 4; ++r) {
        int m = m0 + wr * 64 + mi * 16 + kh * 4 + r;
        if (m >= M) continue;
        float v = acc[mi][ni][r] + bv;
        if (act == 1) v = (v > 20.f) ? v : log1pf(__expf(v));
        Cb[(long)m * ldc + n] = v;
      }
    }
}

// ---------------- weight fp32 -> bf16 hi/lo splitter ----------------
__global__ void wconvert_kernel(const float* __restrict__ src,
                                u16* __restrict__ hi, u16* __restrict__ lo,
                                long n4) {
  long i = (long)blockIdx.x * 256 + threadIdx.x;
  long stride = (long)gridDim.x * 256;
  for (; i < n4; i += stride) {
    float4 v = ((const float4*)src)[i];
    ushort4 h, l;
    split2(v.x, h.x, l.x);
    split2(v.y, h.y, l.y);
    split2(v.z, h.z, l.z);
    split2(v.w, h.w, l.w);
    ((ushort4*)hi)[i] = h;
    ((ushort4*)lo)[i] = l;
  }
}

// ---------------- patch embed + cls insert + pos add ----------------
__global__ void patch_embed_kernel(const float* __restrict__ x,
                                   const float* __restrict__ pw,
                                   const float* __restrict__ pb,
                                   const float* __restrict__ cls,
                                   const float* __restrict__ pos,
                                   float* __restrict__ hidden,
                                   float* __restrict__ residual) {
  int c = blockIdx.x * 256 + threadIdx.x;
  int s = blockIdx.y;
  if (c >= DM) return;
  float val;
  if (s == 256) {
    val = cls[c];
  } else {
    int p = s - (s > 256 ? 1 : 0);
    int gy = p >> 6, gx = p & 63;
    const float* xp = x + gy * 16 * 1024 + gx * 16;
    const float* wp = pw + c * 256;
    float acc = pb[c];
#pragma unroll 4
    for (int ky = 0; ky < 16; ++ky)
#pragma unroll
      for (int kx = 0; kx < 16; ++kx)
        acc += xp[ky * 1024 + kx] * wp[ky * 16 + kx];
    val = acc;
  }
  long idx = (long)s * DM + c;
  hidden[idx] = val + pos[idx];
  residual[idx] = 0.f;
}

// ---- residual += sum(hidden partials); hn = rmsnorm(residual)*w -> bf16 hi/lo ----
__global__ void rmsnorm_kernel(const float* __restrict__ hp, int nparts, long pstr,
                               float* __restrict__ residual,
                               u16* __restrict__ hnh, u16* __restrict__ hnl,
                               const float* __restrict__ w) {
  int t = blockIdx.x;
  float* rrow = residual + (long)t * DM;
  int tid = threadIdx.x;
  float vals[3];
  float ss = 0.f;
#pragma unroll
  for (int i = 0; i < 3; ++i) {
    int c = tid + i * 256;
    float v = rrow[c];
    for (int p = 0; p < nparts; ++p) v += hp[(long)p * pstr + (long)t * DM + c];
    vals[i] = v;
    rrow[c] = v;
    ss += v * v;
  }
#pragma unroll
  for (int o = 32; o; o >>= 1) ss += __shfl_down(ss, o, 64);
  __shared__ float sacc[4];
  if ((tid & 63) == 0) sacc[tid >> 6] = ss;
  __syncthreads();
  float tot = sacc[0] + sacc[1] + sacc[2] + sacc[3];
  float rs = rsqrtf(tot / (float)DM + 1e-5f);
#pragma unroll
  for (int i = 0; i < 3; ++i) {
    int c = tid + i * 256;
    float y = vals[i] * rs * w[c];
    u16 h, l;
    split2(y, h, l);
    hnh[(long)t * DM + c] = h;
    hnl[(long)t * DM + c] = l;
  }
}

// ---- conv+silu (sums SKI partials) -> xc fp32 + hi/lo; plus silu(z) -> zs ----
__global__ void conv_zs_kernel(const float* __restrict__ xz_p,
                               const float* __restrict__ cw,
                               const float* __restrict__ cb,
                               float* __restrict__ xc,
                               u16* __restrict__ xch, u16* __restrict__ xcl,
                               float* __restrict__ zs) {
  const long PZ = (long)L_SEQ * 2 * DI;
  int v = blockIdx.x;
  int tid = threadIdx.x;
  if (v < 1540) {
    int dir = v / 770, vv = v - dir * 770;
    int idx = vv * 256 + tid;
    if (idx >= L_SEQ * (DI / 4)) return;
    int d4 = idx % (DI / 4);
    int t = idx / (DI / 4);
    int d = d4 * 4;
    float wv[4][4];
#pragma unroll
    for (int j = 0; j < 4; ++j) {
      float4 wr4 = *(const float4*)(cw + ((long)dir * DI + d + j) * 4);
      wv[j][0] = wr4.x; wv[j][1] = wr4.y; wv[j][2] = wr4.z; wv[j][3] = wr4.w;
    }
    float4 bv = *(const float4*)(cb + (long)dir * DI + d);
    float a0 = bv.x, a1 = bv.y, a2 = bv.z, a3 = bv.w;
#pragma unroll
    for (int k = 0; k < 4; ++k) {
      int tau = t + k - 3;
      if (tau >= 0) {
        int tsrc = dir ? (L_SEQ - 1 - tau) : tau;
        long o = (long)tsrc * (2 * DI) + d;
        float4 x0 = *(const float4*)(xz_p + o);
        float4 x1 = *(const float4*)(xz_p + o + PZ);
        float4 x2 = *(const float4*)(xz_p + o + 2 * PZ);
        a0 += wv[0][k] * (x0.x + x1.x + x2.x);
        a1 += wv[1][k] * (x0.y + x1.y + x2.y);
        a2 += wv[2][k] * (x0.z + x1.z + x2.z);
        a3 += wv[3][k] * (x0.w + x1.w + x2.w);
      }
    }
    float4 sv;
    sv.x = siluf(a0); sv.y = siluf(a1); sv.z = siluf(a2); sv.w = siluf(a3);
    long o = ((long)dir * L_SEQ + t) * DI + d;
    *(float4*)(xc + o) = sv;
    ushort4 h, lo;
    split2(sv.x, h.x, lo.x);
    split2(sv.y, h.y, lo.y);
    split2(sv.z, h.z, lo.z);
    split2(sv.w, h.w, lo.w);
    *(ushort4*)(xch + o) = h;
    *(ushort4*)(xcl + o) = lo;
  } else {
    int vv = v - 1540;
    int idx = vv * 256 + tid;
    if (idx >= L_SEQ * (DI / 4)) return;
    int d4 = idx % (DI / 4);
    int t = idx / (DI / 4);
    long zo = (long)t * (2 * DI) + DI + d4 * 4;
    float4 z0 = *(const float4*)(xz_p + zo);
    float4 z1 = *(const float4*)(xz_p + zo + PZ);
    float4 z2 = *(const float4*)(xz_p + zo + 2 * PZ);
    float4 sv;
    sv.x = siluf(z0.x + z1.x + z2.x);
    sv.y = siluf(z0.y + z1.y + z2.y);
    sv.z = siluf(z0.z + z1.z + z2.z);
    sv.w = siluf(z0.w + z1.w + z2.w);
    *(float4*)(zs + (long)t * DI + d4 * 4) = sv;
  }
}

// ---------------- fused chunked scan (pass1 + LDS fixup + pass2) ----------------
__global__ __launch_bounds__(256) void scan_all(
    const float* __restrict__ dtb,   // (2,L,DI) softplus'ed
    const float* __restrict__ xc,    // (2,L,DI)
    const float* __restrict__ dbl,   // (2,L,80): cols 48..80 = B,C
    const float* __restrict__ zs,    // (L,DI)
    const float* __restrict__ A_log,
    const float* __restrict__ Dsk,
    float* __restrict__ y) {
  __shared__ float Q[8 * NC * DSTATE];  // 16 KB
  __shared__ float Sv[8 * NC];
  const long LDIlen = (long)L_SEQ * DI;
  int dir = blockIdx.y;
  int d0 = blockIdx.x * 8;
  int tid = threadIdx.x;
  const float* dtp = dtb + dir * LDIlen;
  const float* xcp = xc + dir * LDIlen;
  const float* dblp = dbl + (long)dir * L_SEQ * 80;
  int dl = tid & 7, c = tid >> 3;
  int d = d0 + dl;
  float negA[DSTATE];
#pragma unroll
  for (int n = 0; n < DSTATE; ++n)
    negA[n] = -__expf(A_log[((long)dir * DI + d) * DSTATE + n]);
  int t0 = c * CLEN, t1 = min(t0 + CLEN, L_SEQ);
  {
    float h[DSTATE];
#pragma unroll
    for (int n = 0; n < DSTATE; ++n) h[n] = 0.f;
    float S = 0.f;
    for (int t = t0; t < t1; ++t) {
      float dt = dtp[(long)t * DI + d];
      float u = xcp[(long)t * DI + d];
      float du = dt * u;
      S += dt;
      const float4* B4 = (const float4*)(dblp + (long)t * 80 + DTRANK);
      float4 b0 = B4[0], b1 = B4[1], b2 = B4[2], b3 = B4[3];
      float Bv[DSTATE] = {b0.x, b0.y, b0.z, b0.w, b1.x, b1.y, b1.z, b1.w,
                          b2.x, b2.y, b2.z, b2.w, b3.x, b3.y, b3.z, b3.w};
#pragma unroll
      for (int n = 0; n < DSTATE; ++n)
        h[n] = h[n] * __expf(dt * negA[n]) + du * Bv[n];
    }
    Sv[dl * NC + c] = S;
#pragma unroll
    for (int n = 0; n < DSTATE; ++n) Q[(dl * NC + c) * DSTATE + n] = h[n];
  }
  __syncthreads();
  if (tid < 128) {
    int fdl = tid >> 4, n = tid & 15;
    int fd = d0 + fdl;
    float nA = -__expf(A_log[((long)dir * DI + fd) * DSTATE + n]);
    float h = 0.f;
    for (int cc = 0; cc < NC; ++cc) {
      float S = Sv[fdl * NC + cc];
      float q = Q[(fdl * NC + cc) * DSTATE + n];
      Q[(fdl * NC + cc) * DSTATE + n] = h;
      h = h * __expf(nA * S) + q;
    }
  }
  __syncthreads();
  {
    float h[DSTATE];
#pragma unroll
    for (int n = 0; n < DSTATE; ++n) h[n] = Q[(dl * NC + c) * DSTATE + n];
    float dskip = Dsk[(long)dir * DI + d];
    for (int t = t0; t < t1; ++t) {
      float dt = dtp[(long)t * DI + d];
      float u = xcp[(long)t * DI + d];
      float du = dt * u;
      const float4* B4 = (const float4*)(dblp + (long)t * 80 + DTRANK);
      float4 b0 = B4[0], b1 = B4[1], b2 = B4[2], b3 = B4[3];
      float4 c0 = B4[4], c1 = B4[5], c2 = B4[6], c3 = B4[7];
      float Bv[DSTATE] = {b0.x, b0.y, b0.z, b0.w, b1.x, b1.y, b1.z, b1.w,
                          b2.x, b2.y, b2.z, b2.w, b3.x, b3.y, b3.z, b3.w};
      float Cv[DSTATE] = {c0.x, c0.y, c0.z, c0.w, c1.x, c1.y, c1.z, c1.w,
                          c2.x, c2.y, c2.z, c2.w, c3.x, c3.y, c3.z, c3.w};
      float acc = 0.f;
#pragma unroll
      for (int n = 0; n < DSTATE; ++n) {
        h[n] = h[n] * __expf(dt * negA[n]) + du * Bv[n];
        acc += h[n] * Cv[n];
      }
      int tsrc = dir ? (L_SEQ - 1 - t) : t;
      float sz = zs[(long)tsrc * DI + d];
      y[((long)dir * L_SEQ + tsrc) * DI + d] = (acc + dskip * u) * sz;
    }
  }
}

// ---------------- final rmsnorm(token 256) + head (sums SKO partials) ----------------
__global__ void head_kernel(const float* __restrict__ residual,
                            const float* __restrict__ hp, long pstr,
                            const float* __restrict__ nfw,
                            const float* __restrict__ hw,
                            const float* __restrict__ hb,
                            float* __restrict__ out) {
  int j = blockIdx.x;
  int tid = threadIdx.x;
  const float* r = residual + (long)256 * DM;
  float ss = 0.f, dp = 0.f;
#pragma unroll
  for (int i = 0; i < 3; ++i) {
    int c = tid + i * 256;
    float v = r[c];
    for (int p = 0; p < SKO; ++p) v += hp[(long)p * pstr + (long)256 * DM + c];
    ss += v * v;
    dp += v * nfw[c] * hw[(long)j * DM + c];
  }
#pragma unroll
  for (int o = 32; o; o >>= 1) {
    ss += __shfl_down(ss, o, 64);
    dp += __shfl_down(dp, o, 64);
  }
  __shared__ float s1[4], s2[4];
  if ((tid & 63) == 0) {
    s1[tid >> 6] = ss;
    s2[tid >> 6] = dp;
  }
  __syncthreads();
  if (tid == 0) {
    float tot = s1[0] + s1[1] + s1[2] + s1[3];
    float d = s2[0] + s2[1] + s2[2] + s2[3];
    out[j] = d * rsqrtf(tot / (float)DM + 1e-5f) + hb[j];
  }
}

extern "C" void kernel_launch(void* const* d_in, const int* in_sizes, int n_in,
                              void* d_out, int out_size, void* d_ws, size_t ws_size,
                              hipStream_t stream) {
  const float* x        = (const float*)d_in[0];
  const float* patch_w  = (const float*)d_in[1];
  const float* patch_b  = (const float*)d_in[2];
  const float* cls_tok  = (const float*)d_in[3];
  const float* pos_emb  = (const float*)d_in[4];
  const float* in_proj  = (const float*)d_in[5];
  const float* conv_w   = (const float*)d_in[6];
  const float* conv_b   = (const float*)d_in[7];
  const float* xproj_w  = (const float*)d_in[8];
  const float* dtproj_w = (const float*)d_in[9];
  const float* dtproj_b = (const float*)d_in[10];
  const float* A_log    = (const float*)d_in[11];
  const float* D_skip   = (const float*)d_in[12];
  const float* out_proj = (const float*)d_in[13];
  const float* norm_w   = (const float*)d_in[14];
  const float* norm_f_w = (const float*)d_in[15];
  const float* head_w   = (const float*)d_in[16];
  const float* head_b   = (const float*)d_in[17];
  float* out = (float*)d_out;

  const long PHN = (long)L_SEQ * DM;
  const long PZ  = (long)L_SEQ * 2 * DI;
  const long LDIlen = (long)L_SEQ * DI;
  const long P80 = (long)L_SEQ * 80;

  float* fb = (float*)d_ws;
  float* residual = fb; fb += PHN;
  float* xz_p     = fb; fb += SKI * PZ;
  float* xc       = fb; fb += (long)2 * LDIlen;
  float* zs       = fb; fb += LDIlen;
  float* dbl      = fb; fb += (long)2 * P80;
  float* dbl_p    = fb; fb += (long)2 * SKX * P80;
  float* dtb      = fb; fb += (long)2 * LDIlen;
  float* yb       = fb; fb += (long)2 * LDIlen;
  float* hid_p    = fb; fb += (long)SKO * PHN;

  u16* wsu = (u16*)fb;
  const long N_HN = PHN;
  const long N_XC = (long)2 * LDIlen;
  const long N_WI = (long)DEPTH * 2 * DI * DM;
  const long N_WX = (long)DEPTH * 2 * 80 * DI;
  const long N_WD = (long)DEPTH * 2 * DI * DTRANK;
  const long N_WO = (long)DEPTH * DM * DI;
  u16* hn_h = wsu; wsu += N_HN;
  u16* hn_l = wsu; wsu += N_HN;
  u16* xc_h = wsu; wsu += N_XC;
  u16* xc_l = wsu; wsu += N_XC;
  u16* wi_h = wsu; wsu += N_WI;
  u16* wi_l = wsu; wsu += N_WI;
  u16* wx_h = wsu; wsu += N_WX;
  u16* wx_l = wsu; wsu += N_WX;
  u16* wd_h = wsu; wsu += N_WD;
  u16* wd_l = wsu; wsu += N_WD;
  u16* wo_h = wsu; wsu += N_WO;
  u16* wo_l = wsu; wsu += N_WO;

  wconvert_kernel<<<2048, 256, 0, stream>>>(in_proj,  wi_h, wi_l, N_WI / 4);
  wconvert_kernel<<<512,  256, 0, stream>>>(xproj_w,  wx_h, wx_l, N_WX / 4);
  wconvert_kernel<<<512,  256, 0, stream>>>(dtproj_w, wd_h, wd_l, N_WD / 4);
  wconvert_kernel<<<2048, 256, 0, stream>>>(out_proj, wo_h, wo_l, N_WO / 4);

  patch_embed_kernel<<<dim3(3, L_SEQ), 256, 0, stream>>>(
      x, patch_w, patch_b, cls_tok, pos_emb, hid_p, residual);

  for (int l = 0; l < DEPTH; ++l) {
    const u16* wih = wi_h + (long)l * 2 * DI * DM;
    const u16* wil = wi_l + (long)l * 2 * DI * DM;
    const u16* wxh = wx_h + (long)l * 2 * 80 * DI;
    const u16* wxl = wx_l + (long)l * 2 * 80 * DI;
    const u16* wdh = wd_h + (long)l * 2 * DI * DTRANK;
    const u16* wdl = wd_l + (long)l * 2 * DI * DTRANK;
    const u16* woh = wo_h + (long)l * DM * DI;
    const u16* wol = wo_l + (long)l * DM * DI;
    const float* cw = conv_w + (long)l * 2 * DI * 4;
    const float* cb = conv_b + (long)l * 2 * DI;
    const float* db = dtproj_b + (long)l * 2 * DI;
    const float* Al = A_log + (long)l * 2 * DI * DSTATE;
    const float* Dk = D_skip + (long)l * 2 * DI;
    const float* nw = norm_w + (long)l * DM;

    // 1. rmsnorm
    rmsnorm_kernel<<<L_SEQ, 256, 0, stream>>>(
        hid_p, (l == 0) ? 1 : SKO, PHN, residual, hn_h, hn_l, nw);

    // 2. in_proj, split-K=3 -> xz partials (360 blocks, 8 K-steps)
    gemm128<0><<<dim3(24, 5, SKI), 256, 0, stream>>>(
        hn_h, hn_l, wih, wil, xz_p, L_SEQ, 2 * DI, DM, DM, DM, 2 * DI,
        0, 0, 0, SKI, DM / SKI, PZ, nullptr, 0, 0, nullptr);

    // 3. conv+silu (sums 3 partials) -> xc (+hi/lo); silu(z) -> zs
    conv_zs_kernel<<<2310, 256, 0, stream>>>(xz_p, cw, cb, xc, xc_h, xc_l, zs);

    // 4. x_proj split-K=8 -> dbl partials (80 blocks, 6 K-steps each)
    gemm128<0><<<dim3(1, 5, 2 * SKX), 256, 0, stream>>>(
        xc_h, xc_l, wxh, wxl, dbl_p, L_SEQ, 80, DI, DI, DI, 80,
        LDIlen, (long)80 * DI, (long)SKX * P80, SKX, DI / SKX, P80,
        nullptr, 0, 0, nullptr);

    // 5. dt_proj AMODE2: A = sum of 8 d48 partials; last grid.x column reduces B/C
    gemm128<2><<<dim3(13, 5, 2), 256, 0, stream>>>(
        dbl_p, nullptr, wdh, wdl, dtb, L_SEQ, DI, DTRANK, 80, DTRANK, DI,
        (long)SKX * P80, (long)DI * DTRANK, LDIlen, 1, DTRANK, P80,
        db, DI, 1, dbl);

    // 6. fused chunked scan
    scan_all<<<dim3(192, 2), 256, 0, stream>>>(dtb, xc, dbl, zs, Al, Dk, yb);

    // 7. out_proj, fused yavg (AMODE1), split-K=8 -> hid_p partials
    gemm128<1><<<dim3(6, 5, SKO), 256, 0, stream>>>(
        yb, yb + LDIlen, woh, wol, hid_p, L_SEQ, DM, DI, DI, DI, DM,
        0, 0, 0, SKO, DI / SKO, PHN, nullptr, 0, 0, nullptr);
  }

  head_kernel<<<NCLS, 256, 0, stream>>>(residual, hid_p, PHN,
                                        norm_f_w, head_w, head_b, out);
}